// Round 6
// baseline (571.150 us; speedup 1.0000x reference)
//
#include <hip/hip_runtime.h>

// SABlock: EGNN-style block. N=4, L=256, D=128, P=64, C=4.
//   k_norm_partial/k_norm_finish : global L2 norm of radial -> rnorm[16]
//   k_pack_coord_w : pre-pack c0w1/c1w1 into MFMA A-frag order (bf16), once
//   k_pack_msg_w   : pre-pack msg_w1 A-frags (hj LDS-part | rad LDS-part | z global-part) + msg_w2
//   k_pack_edge_w  : pre-pack edge_w1 z-rows (K=64) and edge_w2 A-frags
//   k_pre_hA   : hA = h@msg_w1[0:128]+msg_b1
//   k_msg_mfma : GEMM1 (K=224) -> silu -> GEMM2 -> m bf16 + masked aggregates
//                v2: 78.9 KB LDS -> 2 blocks/CU; per-phase hidm (128 rows); rad inline
//   k_coord_mfma : coord MLPs on MFMA + coord update epilogue
//   k_node     : node MLP + LayerNorm
//   k_pre_msg  : eA/eB for edge path (uses h_new)
//   k_edge_mfma : GEMM1 (K=64, z) -> silu(+eA+eB) -> GEMM2 (K=128) -> z_new fp32

#define DEV static __device__ __forceinline__

DEV float silu(float x) { return x / (1.0f + __expf(-x)); }

DEV float bf2f(unsigned short u) {
    unsigned int v = ((unsigned int)u) << 16;
    float f;
    __builtin_memcpy(&f, &v, 4);
    return f;
}
DEV unsigned short f2bf(float f) {
    unsigned int x;
    __builtin_memcpy(&x, &f, 4);
    x += 0x7fffu + ((x >> 16) & 1u);
    return (unsigned short)(x >> 16);
}

struct __align__(8) US4 { unsigned short x, y, z, w; };

typedef __bf16 bf16x8 __attribute__((ext_vector_type(8)));
typedef float  f32x4  __attribute__((ext_vector_type(4)));

#define FMA4(acc_, s_, v_) { (acc_).x += (s_)*(v_).x; (acc_).y += (s_)*(v_).y; (acc_).z += (s_)*(v_).z; (acc_).w += (s_)*(v_).w; }

DEV bf16x8 cvt8(const float* p) {
    const float4 a = *reinterpret_cast<const float4*>(p);
    const float4 c = *reinterpret_cast<const float4*>(p + 4);
    bf16x8 r;
    r[0] = (__bf16)a.x; r[1] = (__bf16)a.y; r[2] = (__bf16)a.z; r[3] = (__bf16)a.w;
    r[4] = (__bf16)c.x; r[5] = (__bf16)c.y; r[6] = (__bf16)c.z; r[7] = (__bf16)c.w;
    return r;
}

// ---------------- norm of radial ----------------
__global__ __launch_bounds__(256) void k_norm_partial(const float* __restrict__ coord,
                                                      float* __restrict__ partial)
{
    const int t = threadIdx.x;
    const int r = blockIdx.x * 256 + t;
    const int b = r >> 16, rem = r & 0xFFFF, i = rem >> 8, j = rem & 255;
    const float* ci = coord + (b * 256 + i) * 12;
    const float* cj = coord + (b * 256 + j) * 12;
    float cd[4][3];
    #pragma unroll
    for (int c = 0; c < 4; ++c)
        #pragma unroll
        for (int x = 0; x < 3; ++x)
            cd[c][x] = ci[c * 3 + x] - cj[c * 3 + x];
    float sq[16];
    #pragma unroll
    for (int m = 0; m < 4; ++m)
        #pragma unroll
        for (int p = 0; p < 4; ++p) {
            float v = cd[m][0] * cd[p][0] + cd[m][1] * cd[p][1] + cd[m][2] * cd[p][2];
            sq[m * 4 + p] = v * v;
        }
    #pragma unroll
    for (int s = 1; s < 64; s <<= 1)
        #pragma unroll
        for (int qq = 0; qq < 16; ++qq)
            sq[qq] += __shfl_xor(sq[qq], s, 64);
    __shared__ float red[4][16];
    const int wave = t >> 6, lane = t & 63;
    if (lane == 0)
        #pragma unroll
        for (int qq = 0; qq < 16; ++qq) red[wave][qq] = sq[qq];
    __syncthreads();
    if (t < 16)
        partial[blockIdx.x * 16 + t] = red[0][t] + red[1][t] + red[2][t] + red[3][t];
}

__global__ __launch_bounds__(256) void k_norm_finish(const float* __restrict__ partial,
                                                     float* __restrict__ rnorm)
{
    const int t = threadIdx.x;
    const int cc = t & 15, g = t >> 4;
    float s = 0.f;
    for (int k = 0; k < 64; ++k) s += partial[(g * 64 + k) * 16 + cc];
    __shared__ float red[16][17];
    red[g][cc] = s;
    __syncthreads();
    if (t < 16) {
        float tot = 0.f;
        #pragma unroll
        for (int gg = 0; gg < 16; ++gg) tot += red[gg][t];
        rnorm[t] = 1.0f / fmaxf(sqrtf(tot), 1e-12f);
    }
}

// ---------------- hA only (msg path) ----------------
__global__ __launch_bounds__(128) void k_pre_hA(const float* __restrict__ h,
                                                const float* __restrict__ w1,
                                                const float* __restrict__ b1,
                                                float* __restrict__ hA)
{
    const int r = blockIdx.x;
    const int t = threadIdx.x;
    __shared__ float hl[128];
    hl[t] = h[r * 128 + t];
    __syncthreads();
    float acc = b1[t];
    #pragma unroll 8
    for (int k = 0; k < 128; ++k) acc += hl[k] * w1[k * 128 + t];
    hA[r * 128 + t] = acc;
}

// ---------------- row-precompute for edge path ----------------
__global__ __launch_bounds__(256) void k_pre_msg(const float* __restrict__ h,
                                                 const float* __restrict__ w1,
                                                 const float* __restrict__ b1,
                                                 float* __restrict__ hA,
                                                 float* __restrict__ hB)
{
    const int r = blockIdx.x;
    const int t = threadIdx.x;
    const int half = t >> 7, c = t & 127;
    __shared__ float hl[128];
    if (t < 128) hl[t] = h[r * 128 + t];
    __syncthreads();
    const float* W = w1 + half * 128 * 128;
    float acc = half ? 0.f : b1[c];
    #pragma unroll 8
    for (int k = 0; k < 128; ++k) acc += hl[k] * W[k * 128 + c];
    (half ? hB : hA)[r * 128 + c] = acc;
}

// ---------------- pack msg weights into A-frag order (once) ----------------
// Layout (shorts):
//  [0,16384)      hj frags   kk0..3, rf0..7 : k=kk*32+(l>>4)*8+jj, src row 128+k   (LDS-staged)
//  [16384,20480)  rad frags  rf0..7         : k=(l>>4)*8+jj, src row 256+k if k<16 else 0 (LDS-staged)
//  [20480,28672)  z frags    kk0..1, rf0..7 : k=kk*32+(l>>4)*8+jj, src row 272+k   (global-read)
// wsW2A unchanged.
__global__ __launch_bounds__(256) void k_pack_msg_w(const float* __restrict__ msg_w1,
                                                    const float* __restrict__ msg_w2,
                                                    unsigned short* __restrict__ wsMsgA,
                                                    unsigned short* __restrict__ wsW2A)
{
    const int o = blockIdx.x * 256 + threadIdx.x;    // < 45056
    if (o < 16384) {
        const int jj = o & 7, l = (o >> 3) & 63, rf = (o >> 9) & 7, kk = o >> 12;
        const int k = kk * 32 + ((l >> 4) << 3) + jj;
        const int c = (rf << 4) + (l & 15);
        wsMsgA[o] = f2bf(msg_w1[(128 + k) * 128 + c]);
    } else if (o < 20480) {
        const int o2 = o - 16384;
        const int jj = o2 & 7, l = (o2 >> 3) & 63, rf = (o2 >> 9) & 7;
        const int k = ((l >> 4) << 3) + jj;
        const int c = (rf << 4) + (l & 15);
        wsMsgA[o] = (k < 16) ? f2bf(msg_w1[(256 + k) * 128 + c]) : (unsigned short)0;
    } else if (o < 28672) {
        const int o3 = o - 20480;
        const int jj = o3 & 7, l = (o3 >> 3) & 63, rf = (o3 >> 9) & 7, kk = o3 >> 12;
        const int k = kk * 32 + ((l >> 4) << 3) + jj;
        const int c = (rf << 4) + (l & 15);
        wsMsgA[o] = f2bf(msg_w1[(272 + k) * 128 + c]);
    } else {
        const int o2 = o - 28672;                     // < 16384
        const int jj = o2 & 7, l = (o2 >> 3) & 63, rf = (o2 >> 9) & 7, kk2 = o2 >> 12;
        const int c  = kk2 * 32 + ((l >> 4) << 3) + jj;
        const int c2 = (rf << 4) + (l & 15);
        wsW2A[o2] = f2bf(msg_w2[c * 128 + c2]);
    }
}

// ---------------- pack edge weights into A-frag order (once) ----------------
__global__ __launch_bounds__(256) void k_pack_edge_w(const float* __restrict__ edge_w1,
                                                     const float* __restrict__ edge_w2,
                                                     unsigned short* __restrict__ wE1A,
                                                     unsigned short* __restrict__ wEW2A)
{
    const int o = blockIdx.x * 256 + threadIdx.x;    // < 16384
    if (o < 8192) {
        const int jj = o & 7, l = (o >> 3) & 63, rf = (o >> 9) & 7, kk = o >> 12;
        const int k = kk * 32 + ((l >> 4) << 3) + jj;
        const int c = (rf << 4) + (l & 15);
        wE1A[o] = f2bf(edge_w1[(256 + k) * 128 + c]);
    } else {
        const int o2 = o - 8192;
        const int jj = o2 & 7, l = (o2 >> 3) & 63, rf = (o2 >> 9) & 3, kk2 = o2 >> 11;
        const int k = kk2 * 32 + ((l >> 4) << 3) + jj;
        const int p = (rf << 4) + (l & 15);
        wEW2A[o2] = f2bf(edge_w2[k * 64 + p]);
    }
}

// ---------------- message MLP via MFMA (v2: 2 blocks/CU) ----------------
__global__ __launch_bounds__(512, 4) void k_msg_mfma(
    const float* __restrict__ coord, const float* __restrict__ h,
    const float* __restrict__ z,
    const float* __restrict__ intra, const float* __restrict__ inter,
    const float* __restrict__ hA,
    const unsigned short* __restrict__ wsMsgA,
    const unsigned short* __restrict__ wsW2A,
    const float* __restrict__ msg_b2, const float* __restrict__ rnorm,
    unsigned short* __restrict__ m_out,
    float* __restrict__ aggI, float* __restrict__ aggE)
{
    const int bi = blockIdx.x;
    const int b  = bi >> 8;
    const int t  = threadIdx.x;
    const int w  = t >> 6, l = t & 63, g = l >> 4, l15 = l & 15;

    __shared__ __align__(16) unsigned short A1[20480];        // 40960 B: hj + rad frags
    __shared__ __align__(16) unsigned short hidm[128 * 136];  // 34816 B: per-phase rows (w*16+l15)
    __shared__ float iml[256], eml[256];
    __shared__ float hAl[128], b2l[128];
    __shared__ float cil[12];
    __shared__ float rnl[16];

    {
        const float4* src = reinterpret_cast<const float4*>(wsMsgA);
        float4* dst = reinterpret_cast<float4*>(A1);
        #pragma unroll
        for (int it = 0; it < 5; ++it) dst[it * 512 + t] = src[it * 512 + t];  // 2560 float4 = 40 KB
    }
    if (t < 12) cil[t] = coord[bi * 12 + t];
    if (t < 16) rnl[t] = rnorm[t];
    if (t < 128)      hAl[t] = hA[bi * 128 + t];
    else if (t < 256) b2l[t - 128] = msg_b2[t - 128];
    else {
        const int i2 = t - 256;
        iml[i2] = intra[bi * 256 + i2];
        eml[i2] = inter[bi * 256 + i2];
    }
    __syncthreads();

    float aI[32], aE[32];
    #pragma unroll
    for (int i2 = 0; i2 < 32; ++i2) { aI[i2] = 0.f; aE[i2] = 0.f; }

    const int row = w * 16 + l15;          // this lane's hidm row (per-phase)
    const size_t rb = (size_t)row * 136;   // shorts

    #pragma unroll 1
    for (int cf = 0; cf < 2; ++cf) {
        const int j = w * 32 + cf * 16 + l15;
        const float* hrow = h + (size_t)(b * 256 + j) * 128;
        const float* zrow = z + (size_t)(bi * 256 + j) * 64;

        // rad B-frag inline (K=32 slot: k = g*8+e, real for k<16, zero-padded above)
        bf16x8 radB;
        {
            const float* cj = coord + (size_t)(b * 256 + j) * 12;
            float cd[12];
            #pragma unroll
            for (int x = 0; x < 12; ++x) cd[x] = cil[x] - cj[x];
            #pragma unroll
            for (int e = 0; e < 8; ++e) {
                const int k = g * 8 + e;
                float v = 0.f;
                if (k < 16) {
                    const int mm = k >> 2, pp = k & 3;
                    v = (cd[mm*3+0]*cd[pp*3+0] + cd[mm*3+1]*cd[pp*3+1] + cd[mm*3+2]*cd[pp*3+2]) * rnl[k];
                }
                radB[e] = (__bf16)v;
            }
        }

        // GEMM1: K=224 (hj 128 from LDS A-frags, z 64 from global A-frags, rad 32 from LDS)
        f32x4 a1[8];
        #pragma unroll
        for (int rf = 0; rf < 8; ++rf) a1[rf] = (f32x4){0.f, 0.f, 0.f, 0.f};

        #pragma unroll
        for (int kk = 0; kk < 4; ++kk) {
            const bf16x8 bf = cvt8(hrow + kk * 32 + g * 8);
            #pragma unroll
            for (int rf = 0; rf < 8; ++rf)
                a1[rf] = __builtin_amdgcn_mfma_f32_16x16x32_bf16(
                    *reinterpret_cast<const bf16x8*>(A1 + ((kk * 8 + rf) * 64 + l) * 8), bf, a1[rf], 0, 0, 0);
        }
        #pragma unroll
        for (int kk = 0; kk < 2; ++kk) {
            const bf16x8 bf = cvt8(zrow + kk * 32 + g * 8);
            #pragma unroll
            for (int rf = 0; rf < 8; ++rf)
                a1[rf] = __builtin_amdgcn_mfma_f32_16x16x32_bf16(
                    *reinterpret_cast<const bf16x8*>(wsMsgA + 20480 + ((kk * 8 + rf) * 64 + l) * 8), bf, a1[rf], 0, 0, 0);
        }
        #pragma unroll
        for (int rf = 0; rf < 8; ++rf)
            a1[rf] = __builtin_amdgcn_mfma_f32_16x16x32_bf16(
                *reinterpret_cast<const bf16x8*>(A1 + 16384 + (rf * 64 + l) * 8), radB, a1[rf], 0, 0, 0);

        // hidden = silu(acc + hA[c]) -> bf16 into this lane's hidm row
        #pragma unroll
        for (int rf = 0; rf < 8; ++rf) {
            const int cb = rf * 16 + g * 4;
            union { __bf16 b4[4]; unsigned long long u; } pk;
            #pragma unroll
            for (int r = 0; r < 4; ++r) pk.b4[r] = (__bf16)silu(a1[rf][r] + hAl[cb + r]);
            *reinterpret_cast<unsigned long long*>(hidm + rb + cb) = pk.u;
        }
        __builtin_amdgcn_wave_barrier();

        // GEMM2: m^T = W2^T x hidden^T (W2 A-frags from global/L2)
        f32x4 a2[8];
        #pragma unroll
        for (int rf = 0; rf < 8; ++rf) a2[rf] = (f32x4){0.f, 0.f, 0.f, 0.f};
        #pragma unroll
        for (int kk2 = 0; kk2 < 4; ++kk2) {
            const bf16x8 bf2 = *reinterpret_cast<const bf16x8*>(hidm + rb + kk2 * 32 + g * 8);
            #pragma unroll
            for (int rf = 0; rf < 8; ++rf)
                a2[rf] = __builtin_amdgcn_mfma_f32_16x16x32_bf16(
                    *reinterpret_cast<const bf16x8*>(wsW2A + ((kk2 * 8 + rf) * 64 + l) * 8), bf2, a2[rf], 0, 0, 0);
        }
        __builtin_amdgcn_wave_barrier();

        // epilogue: +b2, agg accumulate, pack m (bf16) over the hidm row
        const float wI = iml[j], wE = eml[j];
        #pragma unroll
        for (int rf = 0; rf < 8; ++rf) {
            const int cb = rf * 16 + g * 4;
            union { __bf16 b4[4]; unsigned long long u; } pk;
            #pragma unroll
            for (int r = 0; r < 4; ++r) {
                const float mval = a2[rf][r] + b2l[cb + r];
                aI[rf * 4 + r] += mval * wI;
                aE[rf * 4 + r] += mval * wE;
                pk.b4[r] = (__bf16)mval;
            }
            *reinterpret_cast<unsigned long long*>(hidm + rb + cb) = pk.u;
        }
        __builtin_amdgcn_wave_barrier();

        // flush this wave's 16 rows -> m_out (coalesced: 16 lanes x 16B per row)
        #pragma unroll
        for (int it = 0; it < 4; ++it) {
            const int c2 = it * 64 + l;
            const int rl = c2 >> 4, oct = c2 & 15;
            const uint4 v = *reinterpret_cast<const uint4*>(hidm + (size_t)(w * 16 + rl) * 136 + oct * 8);
            *reinterpret_cast<uint4*>(m_out + ((size_t)(bi * 256 + w * 32 + cf * 16 + rl)) * 128 + oct * 8) = v;
        }
        __builtin_amdgcn_wave_barrier();
    }

    __syncthreads();   // all waves done with hidm -> safe to alias reduction buffers

    #pragma unroll
    for (int s = 1; s < 16; s <<= 1) {
        #pragma unroll
        for (int i2 = 0; i2 < 32; ++i2) {
            aI[i2] += __shfl_xor(aI[i2], s, 64);
            aE[i2] += __shfl_xor(aE[i2], s, 64);
        }
    }
    float* redf = reinterpret_cast<float*>(hidm);   // redI: [0,1024), redE: [1024,2048) floats
    if (l15 == 0) {
        #pragma unroll
        for (int rf = 0; rf < 8; ++rf)
            #pragma unroll
            for (int r = 0; r < 4; ++r) {
                const int c = rf * 16 + g * 4 + r;
                redf[w * 128 + c]        = aI[rf * 4 + r];
                redf[1024 + w * 128 + c] = aE[rf * 4 + r];
            }
    }
    __syncthreads();
    if (t < 128) {
        float sI = 0.f, sE = 0.f;
        #pragma unroll
        for (int w8 = 0; w8 < 8; ++w8) { sI += redf[w8 * 128 + t]; sE += redf[1024 + w8 * 128 + t]; }
        aggI[bi * 128 + t] = sI;
        aggE[bi * 128 + t] = sE;
    }
}

// ---------------- pack coord weights into A-fragment order (once) ----------------
__global__ __launch_bounds__(256) void k_pack_coord_w(const float* __restrict__ c0w1,
                                                      const float* __restrict__ c1w1,
                                                      unsigned short* __restrict__ wsA)
{
    const int o = blockIdx.x * 256 + threadIdx.x;    // < 32768
    const int p  = o >> 14;
    const int r  = o & 16383;
    const int jj = r & 7, l = (r >> 3) & 63, rf = (r >> 9) & 7, kk = r >> 12;
    const int k = kk * 32 + ((l >> 4) << 3) + jj;
    const int c = (rf << 4) + (l & 15);
    const float* W = p ? c1w1 : c0w1;
    wsA[o] = f2bf(W[k * 128 + c]);
}

// ---------------- coord update via MFMA ----------------
__global__ __launch_bounds__(512) void k_coord_mfma(
    const float* __restrict__ coord,
    const unsigned short* __restrict__ m_in,
    const float* __restrict__ intra, const float* __restrict__ inter,
    const unsigned short* __restrict__ wsA,
    const float* __restrict__ c0w2, const float* __restrict__ c1w2,
    float* __restrict__ coord_out)
{
    const int bi = blockIdx.x;
    const int b  = bi >> 8;
    const int t  = threadIdx.x;
    const int w  = t >> 6;
    const int l  = t & 63;
    const int g  = l >> 4;
    const int l15 = l & 15;

    __shared__ __align__(16) unsigned short Apk[2 * 16384];
    __shared__ __align__(16) float W2l[2 * 128 * 4];
    __shared__ float iml[256], eml[256];
    __shared__ float cil[12];
    __shared__ float redC[8][12];
    __shared__ float redD[8];

    {
        const float4* srcA = reinterpret_cast<const float4*>(wsA);
        float4* dstA = reinterpret_cast<float4*>(Apk);
        for (int idx = t; idx < 4096; idx += 512) dstA[idx] = srcA[idx];
        if (t < 512) { W2l[t] = c0w2[t]; W2l[512 + t] = c1w2[t]; }
        if (t < 256) { iml[t] = intra[bi * 256 + t]; eml[t] = inter[bi * 256 + t]; }
        if (t < 12)  cil[t] = coord[bi * 12 + t];
    }
    __syncthreads();

    f32x4 acc[2][2][8];
    #pragma unroll
    for (int p = 0; p < 2; ++p)
        #pragma unroll
        for (int cf = 0; cf < 2; ++cf)
            #pragma unroll
            for (int rf = 0; rf < 8; ++rf)
                acc[p][cf][rf] = (f32x4){0.f, 0.f, 0.f, 0.f};

    #pragma unroll
    for (int kk = 0; kk < 4; ++kk) {
        bf16x8 bfr[2];
        #pragma unroll
        for (int cf = 0; cf < 2; ++cf) {
            const size_t mo = ((size_t)(bi * 256 + w * 32 + cf * 16 + l15)) * 128 + kk * 32 + g * 8;
            bfr[cf] = *reinterpret_cast<const bf16x8*>(m_in + mo);
        }
        #pragma unroll
        for (int rf = 0; rf < 8; ++rf) {
            const bf16x8 a0 = *reinterpret_cast<const bf16x8*>(Apk + ((kk * 8 + rf) * 64 + l) * 8);
            const bf16x8 a1 = *reinterpret_cast<const bf16x8*>(Apk + 16384 + ((kk * 8 + rf) * 64 + l) * 8);
            acc[0][0][rf] = __builtin_amdgcn_mfma_f32_16x16x32_bf16(a0, bfr[0], acc[0][0][rf], 0, 0, 0);
            acc[0][1][rf] = __builtin_amdgcn_mfma_f32_16x16x32_bf16(a0, bfr[1], acc[0][1][rf], 0, 0, 0);
            acc[1][0][rf] = __builtin_amdgcn_mfma_f32_16x16x32_bf16(a1, bfr[0], acc[1][0][rf], 0, 0, 0);
            acc[1][1][rf] = __builtin_amdgcn_mfma_f32_16x16x32_bf16(a1, bfr[1], acc[1][1][rf], 0, 0, 0);
        }
    }

    float wf[2][2][4];
    #pragma unroll
    for (int p = 0; p < 2; ++p)
        #pragma unroll
        for (int cf = 0; cf < 2; ++cf)
            #pragma unroll
            for (int pc = 0; pc < 4; ++pc) wf[p][cf][pc] = 0.f;

    #pragma unroll
    for (int p = 0; p < 2; ++p)
        #pragma unroll
        for (int rf = 0; rf < 8; ++rf)
            #pragma unroll
            for (int r = 0; r < 4; ++r) {
                const int c = rf * 16 + g * 4 + r;
                const float4 w2 = *reinterpret_cast<const float4*>(&W2l[(p * 128 + c) * 4]);
                #pragma unroll
                for (int cf = 0; cf < 2; ++cf) {
                    const float hid = silu(acc[p][cf][rf][r]);
                    wf[p][cf][0] += hid * w2.x;
                    wf[p][cf][1] += hid * w2.y;
                    wf[p][cf][2] += hid * w2.z;
                    wf[p][cf][3] += hid * w2.w;
                }
            }

    float accC[12];
    #pragma unroll
    for (int q2 = 0; q2 < 12; ++q2) accC[q2] = 0.f;
    float dacc = 0.f;

    #pragma unroll
    for (int cf = 0; cf < 2; ++cf) {
        float w0c[4], w1c[4];
        #pragma unroll
        for (int pc = 0; pc < 4; ++pc) { w0c[pc] = wf[0][cf][pc]; w1c[pc] = wf[1][cf][pc]; }
        #pragma unroll
        for (int pc = 0; pc < 4; ++pc) {
            w0c[pc] += __shfl_xor(w0c[pc], 16, 64); w0c[pc] += __shfl_xor(w0c[pc], 32, 64);
            w1c[pc] += __shfl_xor(w1c[pc], 16, 64); w1c[pc] += __shfl_xor(w1c[pc], 32, 64);
        }
        const int j = w * 32 + cf * 16 + l15;
        const float im = iml[j], em = eml[j];
        float wt[4];
        #pragma unroll
        for (int pc = 0; pc < 4; ++pc) wt[pc] = w0c[pc] * im + w1c[pc] * em;
        const float* cjp = coord + (size_t)(b * 256 + j) * 12;
        const float4 cj0 = *reinterpret_cast<const float4*>(cjp);
        const float4 cj1 = *reinterpret_cast<const float4*>(cjp + 4);
        const float4 cj2 = *reinterpret_cast<const float4*>(cjp + 8);
        accC[0]  += (cil[0]  - cj0.x) * wt[0];
        accC[1]  += (cil[1]  - cj0.y) * wt[0];
        accC[2]  += (cil[2]  - cj0.z) * wt[0];
        accC[3]  += (cil[3]  - cj0.w) * wt[1];
        accC[4]  += (cil[4]  - cj1.x) * wt[1];
        accC[5]  += (cil[5]  - cj1.y) * wt[1];
        accC[6]  += (cil[6]  - cj1.z) * wt[2];
        accC[7]  += (cil[7]  - cj1.w) * wt[2];
        accC[8]  += (cil[8]  - cj2.x) * wt[2];
        accC[9]  += (cil[9]  - cj2.y) * wt[3];
        accC[10] += (cil[10] - cj2.z) * wt[3];
        accC[11] += (cil[11] - cj2.w) * wt[3];
        dacc += im + em;
    }
    #pragma unroll
    for (int s = 1; s < 16; s <<= 1) {
        #pragma unroll
        for (int q2 = 0; q2 < 12; ++q2) accC[q2] += __shfl_xor(accC[q2], s, 64);
        dacc += __shfl_xor(dacc, s, 64);
    }
    if (l == 0) {
        #pragma unroll
        for (int q2 = 0; q2 < 12; ++q2) redC[w][q2] = accC[q2];
        redD[w] = dacc;
    }
    __syncthreads();
    if (t < 12) {
        float s = 0.f, d = 0.f;
        #pragma unroll
        for (int ww = 0; ww < 8; ++ww) { s += redC[ww][t]; d += redD[ww]; }
        d += 2.56e-4f;   // L * 1e-6
        coord_out[bi * 12 + t] = coord[bi * 12 + t] + s / d;
    }
}

// ---------------- node update + LayerNorm ----------------
__global__ __launch_bounds__(128) void k_node(
    const float* __restrict__ h,
    const float* __restrict__ aggI, const float* __restrict__ aggE,
    const float* __restrict__ rel0, const float* __restrict__ rel1,
    const float* __restrict__ nw1, const float* __restrict__ nb1,
    const float* __restrict__ nw2, const float* __restrict__ nb2,
    const float* __restrict__ lnw, const float* __restrict__ lnb,
    float* __restrict__ h_out)
{
    const int r = blockIdx.x, t = threadIdx.x;
    __shared__ float hl[128], aIl[128], aEl[128], a0l[128], a1l[128], hidl[128];
    hl[t]  = h[r * 128 + t];
    aIl[t] = aggI[r * 128 + t];
    aEl[t] = aggE[r * 128 + t];
    __syncthreads();
    float a0 = 0.f, a1 = 0.f;
    #pragma unroll 8
    for (int k = 0; k < 128; ++k) { a0 += aIl[k] * rel0[k * 128 + t]; a1 += aEl[k] * rel1[k * 128 + t]; }
    a0l[t] = a0; a1l[t] = a1;
    __syncthreads();
    float pre = nb1[t];
    #pragma unroll 8
    for (int k = 0; k < 128; ++k) pre += hl[k]  * nw1[k * 128 + t];
    #pragma unroll 8
    for (int k = 0; k < 128; ++k) pre += a0l[k] * nw1[(128 + k) * 128 + t];
    #pragma unroll 8
    for (int k = 0; k < 128; ++k) pre += a1l[k] * nw1[(256 + k) * 128 + t];
    hidl[t] = silu(pre);
    __syncthreads();
    float upd = nb2[t];
    #pragma unroll 8
    for (int k = 0; k < 128; ++k) upd += hidl[k] * nw2[k * 128 + t];
    const float x = hl[t] + upd;
    float s = x, s2 = x * x;
    #pragma unroll
    for (int d = 1; d < 64; d <<= 1) { s += __shfl_xor(s, d, 64); s2 += __shfl_xor(s2, d, 64); }
    __shared__ float rs[2], rs2[2];
    const int wv = t >> 6;
    if ((t & 63) == 0) { rs[wv] = s; rs2[wv] = s2; }
    __syncthreads();
    const float S = rs[0] + rs[1], S2 = rs2[0] + rs2[1];
    const float mu = S * (1.f / 128.f);
    const float var = S2 * (1.f / 128.f) - mu * mu;
    h_out[r * 128 + t] = (x - mu) * rsqrtf(var + 1e-5f) * lnw[t] + lnb[t];
}

// ---------------- edge update via MFMA ----------------
__global__ __launch_bounds__(512) void k_edge_mfma(
    const float* __restrict__ z,
    const float* __restrict__ eA, const float* __restrict__ eB,
    const unsigned short* __restrict__ wE1A,
    const unsigned short* __restrict__ wEW2A,
    const float* __restrict__ eb2,
    float* __restrict__ z_out)
{
    const int bi = blockIdx.x;
    const int b  = bi >> 8;
    const int t  = threadIdx.x;
    const int w  = t >> 6, l = t & 63, g = l >> 4, l15 = l & 15;

    __shared__ __align__(16) unsigned short hidm[256 * 136];  // rows reused fp32 for z_new
    __shared__ float eAl[128];
    __shared__ float eb2l[64];

    if (t < 128)      eAl[t] = eA[bi * 128 + t];
    else if (t < 192) eb2l[t - 128] = eb2[t - 128];
    __syncthreads();

    #pragma unroll 1
    for (int cf = 0; cf < 2; ++cf) {
        asm volatile("" ::: "memory");
        const int j = w * 32 + cf * 16 + l15;
        const float* zrow = z + (size_t)(bi * 256 + j) * 64;

        f32x4 a1[8];
        #pragma unroll
        for (int rf = 0; rf < 8; ++rf) a1[rf] = (f32x4){0.f, 0.f, 0.f, 0.f};
        #pragma unroll
        for (int kk = 0; kk < 2; ++kk) {
            const bf16x8 bf = cvt8(zrow + kk * 32 + g * 8);
            #pragma unroll
            for (int rf = 0; rf < 8; ++rf)
                a1[rf] = __builtin_amdgcn_mfma_f32_16x16x32_bf16(
                    *reinterpret_cast<const bf16x8*>(wE1A + ((kk * 8 + rf) * 64 + l) * 8), bf, a1[rf], 0, 0, 0);
        }

        const float* eBrow = eB + (size_t)(b * 256 + j) * 128;
        #pragma unroll
        for (int rf = 0; rf < 8; ++rf) {
            const int cb = rf * 16 + g * 4;
            const float4 e4 = *reinterpret_cast<const float4*>(eBrow + cb);
            union { __bf16 b4[4]; unsigned long long u; } pk;
            pk.b4[0] = (__bf16)silu(a1[rf][0] + eAl[cb + 0] + e4.x);
            pk.b4[1] = (__bf16)silu(a1[rf][1] + eAl[cb + 1] + e4.y);
            pk.b4[2] = (__bf16)silu(a1[rf][2] + eAl[cb + 2] + e4.z);
            pk.b4[3] = (__bf16)silu(a1[rf][3] + eAl[cb + 3] + e4.w);
            *reinterpret_cast<unsigned long long*>(hidm + (size_t)j * 136 + cb) = pk.u;
        }
        __builtin_amdgcn_wave_barrier();

        f32x4 a2[4];
        #pragma unroll
        for (int rf = 0; rf < 4; ++rf) a2[rf] = (f32x4){0.f, 0.f, 0.f, 0.f};
        #pragma unroll
        for (int kk2 = 0; kk2 < 4; ++kk2) {
            const bf16x8 bf2 = *reinterpret_cast<const bf16x8*>(hidm + (size_t)j * 136 + kk2 * 32 + g * 8);
            #pragma unroll
            for (int rf = 0; rf < 4; ++rf)
                a2[rf] = __builtin_amdgcn_mfma_f32_16x16x32_bf16(
                    *reinterpret_cast<const bf16x8*>(wEW2A + ((kk2 * 4 + rf) * 64 + l) * 8), bf2, a2[rf], 0, 0, 0);
        }
        __builtin_amdgcn_wave_barrier();

        float* zst = reinterpret_cast<float*>(hidm + (size_t)j * 136);
        #pragma unroll
        for (int rf = 0; rf < 4; ++rf) {
            const int p0 = rf * 16 + g * 4;
            float4 v;
            v.x = a2[rf][0] + eb2l[p0 + 0];
            v.y = a2[rf][1] + eb2l[p0 + 1];
            v.z = a2[rf][2] + eb2l[p0 + 2];
            v.w = a2[rf][3] + eb2l[p0 + 3];
            *reinterpret_cast<float4*>(zst + p0) = v;
        }
        __builtin_amdgcn_wave_barrier();
    }

    #pragma unroll
    for (int it = 0; it < 8; ++it) {
        const int chunk = it * 64 + l;
        const int jl = chunk >> 4, oct = chunk & 15;
        const int jr = w * 32 + jl;
        const float4 v = *reinterpret_cast<const float4*>(
            reinterpret_cast<const float*>(hidm + (size_t)jr * 136) + oct * 4);
        *reinterpret_cast<float4*>(z_out + (size_t)(bi * 256 + jr) * 64 + oct * 4) = v;
    }
}

extern "C" void kernel_launch(void* const* d_in, const int* in_sizes, int n_in,
                              void* d_out, int out_size, void* d_ws, size_t ws_size,
                              hipStream_t stream)
{
    (void)in_sizes; (void)n_in; (void)out_size; (void)ws_size;
    const float* coord  = (const float*)d_in[2];
    const float* h      = (const float*)d_in[3];
    const float* z      = (const float*)d_in[4];
    const float* intra  = (const float*)d_in[5];
    const float* inter  = (const float*)d_in[6];
    const float* msg_w1 = (const float*)d_in[7];
    const float* msg_b1 = (const float*)d_in[8];
    const float* msg_w2 = (const float*)d_in[9];
    const float* msg_b2 = (const float*)d_in[10];
    const float* rel_w0 = (const float*)d_in[11];
    const float* rel_w1 = (const float*)d_in[12];
    const float* node_w1= (const float*)d_in[13];
    const float* node_b1= (const float*)d_in[14];
    const float* node_w2= (const float*)d_in[15];
    const float* node_b2= (const float*)d_in[16];
    const float* edge_w1= (const float*)d_in[17];
    const float* edge_b1= (const float*)d_in[18];
    const float* edge_w2= (const float*)d_in[19];
    const float* edge_b2= (const float*)d_in[20];
    const float* c0w1   = (const float*)d_in[21];
    const float* c0w2   = (const float*)d_in[23];
    const float* c1w1   = (const float*)d_in[24];
    const float* c1w2   = (const float*)d_in[26];
    const float* lnw    = (const float*)d_in[27];
    const float* lnb    = (const float*)d_in[28];

    float* out       = (float*)d_out;
    float* coord_out = out;                       // [N,L,C,3]   12288
    float* h_out     = out + 12288;               // [N,L,D]     131072
    float* z_out     = out + 12288 + 131072;      // [N,L,L,P]   16777216

    float* ws      = (float*)d_ws;
    float* partial = ws;                          // 16384
    float* rnorm   = ws + 16384;
    float* hA      = ws + 16448;                  // 131072
    float* hB      = hA + 131072;                 // (unused, layout kept)
    float* aggI    = hB + 131072;
    float* aggE    = aggI + 131072;
    float* eA      = aggE + 131072;
    float* eB      = eA + 131072;
    unsigned short* wsA    = (unsigned short*)(eB + 131072);  // 32768 us (coord A-frags)
    unsigned short* wsMsgA = wsA + 32768;                     // 28672 us (msg GEMM1 A-frags)
    unsigned short* wsW2A  = wsMsgA + 28672;                  // 16384 us (msg W2 A-frags)
    unsigned short* wsE1A  = wsW2A + 16384;                   //  8192 us (edge GEMM1 A-frags)
    unsigned short* wsEW2A = wsE1A + 8192;                    //  8192 us (edge W2 A-frags)
    // m (bf16) lives in the z_new output region (67 MB exact fit, consumed before k_edge).
    unsigned short* m_bf = (unsigned short*)z_out;

    k_norm_partial<<<1024, 256, 0, stream>>>(coord, partial);
    k_norm_finish<<<1, 256, 0, stream>>>(partial, rnorm);
    k_pack_coord_w<<<128, 256, 0, stream>>>(c0w1, c1w1, wsA);
    k_pack_msg_w<<<176, 256, 0, stream>>>(msg_w1, msg_w2, wsMsgA, wsW2A);
    k_pack_edge_w<<<64, 256, 0, stream>>>(edge_w1, edge_w2, wsE1A, wsEW2A);
    k_pre_hA<<<1024, 128, 0, stream>>>(h, msg_w1, msg_b1, hA);
    k_msg_mfma<<<1024, 512, 0, stream>>>(coord, h, z, intra, inter, hA,
                                         wsMsgA, wsW2A, msg_b2, rnorm,
                                         m_bf, aggI, aggE);
    k_coord_mfma<<<1024, 512, 0, stream>>>(coord, m_bf, intra, inter, wsA,
                                           c0w2, c1w2, coord_out);
    k_node<<<1024, 128, 0, stream>>>(h, aggI, aggE, rel_w0, rel_w1,
                                     node_w1, node_b1, node_w2, node_b2, lnw, lnb, h_out);
    k_pre_msg<<<1024, 256, 0, stream>>>(h_out, edge_w1, edge_b1, eA, eB);
    k_edge_mfma<<<1024, 512, 0, stream>>>(z, eA, eB, wsE1A, wsEW2A, edge_b2, z_out);
}

// Round 7
// 358.938 us; speedup vs baseline: 1.5912x; 1.5912x over previous
//
#include <hip/hip_runtime.h>

// SABlock: EGNN-style block. N=4, L=256, D=128, P=64, C=4.
//   k_norm_partial/k_norm_finish : global L2 norm of radial -> rnorm[16]
//   k_pack_coord_w : pre-pack c0w1/c1w1 into MFMA A-frag order (bf16), once
//   k_pack_msg_w   : pre-pack msg_w1 A-frags (hj LDS-part | rad LDS-part | z global-part) + msg_w2
//   k_pack_edge_w  : pre-pack edge_w1 z-rows (K=64) and edge_w2 A-frags
//   k_pre_hA   : hA = h@msg_w1[0:128]+msg_b1
//   k_msg_mfma : GEMM1 (K=224) -> silu -> GEMM2 -> m bf16 + masked aggregates
//                v3: 78.9 KB LDS (2 blocks/CU); NO min-waves launch bound (R6's ",4"
//                capped VGPR at 64 -> scratch spills -> 1 GB HBM traffic, 3x slower)
//   k_coord_mfma : coord MLPs on MFMA + coord update epilogue
//   k_node     : node MLP + LayerNorm
//   k_pre_msg  : eA/eB for edge path (uses h_new)
//   k_edge_mfma : GEMM1 (K=64, z) -> silu(+eA+eB) -> GEMM2 (K=128) -> z_new fp32

#define DEV static __device__ __forceinline__

DEV float silu(float x) { return x / (1.0f + __expf(-x)); }

DEV float bf2f(unsigned short u) {
    unsigned int v = ((unsigned int)u) << 16;
    float f;
    __builtin_memcpy(&f, &v, 4);
    return f;
}
DEV unsigned short f2bf(float f) {
    unsigned int x;
    __builtin_memcpy(&x, &f, 4);
    x += 0x7fffu + ((x >> 16) & 1u);
    return (unsigned short)(x >> 16);
}

struct __align__(8) US4 { unsigned short x, y, z, w; };

typedef __bf16 bf16x8 __attribute__((ext_vector_type(8)));
typedef float  f32x4  __attribute__((ext_vector_type(4)));

#define FMA4(acc_, s_, v_) { (acc_).x += (s_)*(v_).x; (acc_).y += (s_)*(v_).y; (acc_).z += (s_)*(v_).z; (acc_).w += (s_)*(v_).w; }

DEV bf16x8 cvt8(const float* p) {
    const float4 a = *reinterpret_cast<const float4*>(p);
    const float4 c = *reinterpret_cast<const float4*>(p + 4);
    bf16x8 r;
    r[0] = (__bf16)a.x; r[1] = (__bf16)a.y; r[2] = (__bf16)a.z; r[3] = (__bf16)a.w;
    r[4] = (__bf16)c.x; r[5] = (__bf16)c.y; r[6] = (__bf16)c.z; r[7] = (__bf16)c.w;
    return r;
}

// ---------------- norm of radial ----------------
__global__ __launch_bounds__(256) void k_norm_partial(const float* __restrict__ coord,
                                                      float* __restrict__ partial)
{
    const int t = threadIdx.x;
    const int r = blockIdx.x * 256 + t;
    const int b = r >> 16, rem = r & 0xFFFF, i = rem >> 8, j = rem & 255;
    const float* ci = coord + (b * 256 + i) * 12;
    const float* cj = coord + (b * 256 + j) * 12;
    float cd[4][3];
    #pragma unroll
    for (int c = 0; c < 4; ++c)
        #pragma unroll
        for (int x = 0; x < 3; ++x)
            cd[c][x] = ci[c * 3 + x] - cj[c * 3 + x];
    float sq[16];
    #pragma unroll
    for (int m = 0; m < 4; ++m)
        #pragma unroll
        for (int p = 0; p < 4; ++p) {
            float v = cd[m][0] * cd[p][0] + cd[m][1] * cd[p][1] + cd[m][2] * cd[p][2];
            sq[m * 4 + p] = v * v;
        }
    #pragma unroll
    for (int s = 1; s < 64; s <<= 1)
        #pragma unroll
        for (int qq = 0; qq < 16; ++qq)
            sq[qq] += __shfl_xor(sq[qq], s, 64);
    __shared__ float red[4][16];
    const int wave = t >> 6, lane = t & 63;
    if (lane == 0)
        #pragma unroll
        for (int qq = 0; qq < 16; ++qq) red[wave][qq] = sq[qq];
    __syncthreads();
    if (t < 16)
        partial[blockIdx.x * 16 + t] = red[0][t] + red[1][t] + red[2][t] + red[3][t];
}

__global__ __launch_bounds__(256) void k_norm_finish(const float* __restrict__ partial,
                                                     float* __restrict__ rnorm)
{
    const int t = threadIdx.x;
    const int cc = t & 15, g = t >> 4;
    float s = 0.f;
    for (int k = 0; k < 64; ++k) s += partial[(g * 64 + k) * 16 + cc];
    __shared__ float red[16][17];
    red[g][cc] = s;
    __syncthreads();
    if (t < 16) {
        float tot = 0.f;
        #pragma unroll
        for (int gg = 0; gg < 16; ++gg) tot += red[gg][t];
        rnorm[t] = 1.0f / fmaxf(sqrtf(tot), 1e-12f);
    }
}

// ---------------- hA only (msg path) ----------------
__global__ __launch_bounds__(128) void k_pre_hA(const float* __restrict__ h,
                                                const float* __restrict__ w1,
                                                const float* __restrict__ b1,
                                                float* __restrict__ hA)
{
    const int r = blockIdx.x;
    const int t = threadIdx.x;
    __shared__ float hl[128];
    hl[t] = h[r * 128 + t];
    __syncthreads();
    float acc = b1[t];
    #pragma unroll 8
    for (int k = 0; k < 128; ++k) acc += hl[k] * w1[k * 128 + t];
    hA[r * 128 + t] = acc;
}

// ---------------- row-precompute for edge path ----------------
__global__ __launch_bounds__(256) void k_pre_msg(const float* __restrict__ h,
                                                 const float* __restrict__ w1,
                                                 const float* __restrict__ b1,
                                                 float* __restrict__ hA,
                                                 float* __restrict__ hB)
{
    const int r = blockIdx.x;
    const int t = threadIdx.x;
    const int half = t >> 7, c = t & 127;
    __shared__ float hl[128];
    if (t < 128) hl[t] = h[r * 128 + t];
    __syncthreads();
    const float* W = w1 + half * 128 * 128;
    float acc = half ? 0.f : b1[c];
    #pragma unroll 8
    for (int k = 0; k < 128; ++k) acc += hl[k] * W[k * 128 + c];
    (half ? hB : hA)[r * 128 + c] = acc;
}

// ---------------- pack msg weights into A-frag order (once) ----------------
// Layout (shorts):
//  [0,16384)      hj frags   kk0..3, rf0..7 : k=kk*32+(l>>4)*8+jj, src row 128+k   (LDS-staged)
//  [16384,20480)  rad frags  rf0..7         : k=(l>>4)*8+jj, src row 256+k if k<16 else 0 (LDS-staged)
//  [20480,28672)  z frags    kk0..1, rf0..7 : k=kk*32+(l>>4)*8+jj, src row 272+k   (global-read)
// wsW2A unchanged.
__global__ __launch_bounds__(256) void k_pack_msg_w(const float* __restrict__ msg_w1,
                                                    const float* __restrict__ msg_w2,
                                                    unsigned short* __restrict__ wsMsgA,
                                                    unsigned short* __restrict__ wsW2A)
{
    const int o = blockIdx.x * 256 + threadIdx.x;    // < 45056
    if (o < 16384) {
        const int jj = o & 7, l = (o >> 3) & 63, rf = (o >> 9) & 7, kk = o >> 12;
        const int k = kk * 32 + ((l >> 4) << 3) + jj;
        const int c = (rf << 4) + (l & 15);
        wsMsgA[o] = f2bf(msg_w1[(128 + k) * 128 + c]);
    } else if (o < 20480) {
        const int o2 = o - 16384;
        const int jj = o2 & 7, l = (o2 >> 3) & 63, rf = (o2 >> 9) & 7;
        const int k = ((l >> 4) << 3) + jj;
        const int c = (rf << 4) + (l & 15);
        wsMsgA[o] = (k < 16) ? f2bf(msg_w1[(256 + k) * 128 + c]) : (unsigned short)0;
    } else if (o < 28672) {
        const int o3 = o - 20480;
        const int jj = o3 & 7, l = (o3 >> 3) & 63, rf = (o3 >> 9) & 7, kk = o3 >> 12;
        const int k = kk * 32 + ((l >> 4) << 3) + jj;
        const int c = (rf << 4) + (l & 15);
        wsMsgA[o] = f2bf(msg_w1[(272 + k) * 128 + c]);
    } else {
        const int o2 = o - 28672;                     // < 16384
        const int jj = o2 & 7, l = (o2 >> 3) & 63, rf = (o2 >> 9) & 7, kk2 = o2 >> 12;
        const int c  = kk2 * 32 + ((l >> 4) << 3) + jj;
        const int c2 = (rf << 4) + (l & 15);
        wsW2A[o2] = f2bf(msg_w2[c * 128 + c2]);
    }
}

// ---------------- pack edge weights into A-frag order (once) ----------------
__global__ __launch_bounds__(256) void k_pack_edge_w(const float* __restrict__ edge_w1,
                                                     const float* __restrict__ edge_w2,
                                                     unsigned short* __restrict__ wE1A,
                                                     unsigned short* __restrict__ wEW2A)
{
    const int o = blockIdx.x * 256 + threadIdx.x;    // < 16384
    if (o < 8192) {
        const int jj = o & 7, l = (o >> 3) & 63, rf = (o >> 9) & 7, kk = o >> 12;
        const int k = kk * 32 + ((l >> 4) << 3) + jj;
        const int c = (rf << 4) + (l & 15);
        wE1A[o] = f2bf(edge_w1[(256 + k) * 128 + c]);
    } else {
        const int o2 = o - 8192;
        const int jj = o2 & 7, l = (o2 >> 3) & 63, rf = (o2 >> 9) & 3, kk2 = o2 >> 11;
        const int k = kk2 * 32 + ((l >> 4) << 3) + jj;
        const int p = (rf << 4) + (l & 15);
        wEW2A[o2] = f2bf(edge_w2[k * 64 + p]);
    }
}

// ---------------- message MLP via MFMA (v3: LDS diet, default reg budget) ----------------
__global__ __launch_bounds__(512) void k_msg_mfma(
    const float* __restrict__ coord, const float* __restrict__ h,
    const float* __restrict__ z,
    const float* __restrict__ intra, const float* __restrict__ inter,
    const float* __restrict__ hA,
    const unsigned short* __restrict__ wsMsgA,
    const unsigned short* __restrict__ wsW2A,
    const float* __restrict__ msg_b2, const float* __restrict__ rnorm,
    unsigned short* __restrict__ m_out,
    float* __restrict__ aggI, float* __restrict__ aggE)
{
    const int bi = blockIdx.x;
    const int b  = bi >> 8;
    const int t  = threadIdx.x;
    const int w  = t >> 6, l = t & 63, g = l >> 4, l15 = l & 15;

    __shared__ __align__(16) unsigned short A1[20480];        // 40960 B: hj + rad frags
    __shared__ __align__(16) unsigned short hidm[128 * 136];  // 34816 B: per-phase rows (w*16+l15)
    __shared__ float iml[256], eml[256];
    __shared__ float hAl[128], b2l[128];
    __shared__ float cil[12];
    __shared__ float rnl[16];

    {
        const float4* src = reinterpret_cast<const float4*>(wsMsgA);
        float4* dst = reinterpret_cast<float4*>(A1);
        #pragma unroll
        for (int it = 0; it < 5; ++it) dst[it * 512 + t] = src[it * 512 + t];  // 2560 float4 = 40 KB
    }
    if (t < 12) cil[t] = coord[bi * 12 + t];
    if (t < 16) rnl[t] = rnorm[t];
    if (t < 128)      hAl[t] = hA[bi * 128 + t];
    else if (t < 256) b2l[t - 128] = msg_b2[t - 128];
    else {
        const int i2 = t - 256;
        iml[i2] = intra[bi * 256 + i2];
        eml[i2] = inter[bi * 256 + i2];
    }
    __syncthreads();

    float aI[32], aE[32];
    #pragma unroll
    for (int i2 = 0; i2 < 32; ++i2) { aI[i2] = 0.f; aE[i2] = 0.f; }

    const int row = w * 16 + l15;          // this lane's hidm row (per-phase)
    const size_t rb = (size_t)row * 136;   // shorts

    #pragma unroll 1
    for (int cf = 0; cf < 2; ++cf) {
        const int j = w * 32 + cf * 16 + l15;
        const float* hrow = h + (size_t)(b * 256 + j) * 128;
        const float* zrow = z + (size_t)(bi * 256 + j) * 64;

        // rad B-frag inline (K=32 slot: k = g*8+e, real for k<16, zero-padded above)
        bf16x8 radB;
        {
            const float* cj = coord + (size_t)(b * 256 + j) * 12;
            float cd[12];
            #pragma unroll
            for (int x = 0; x < 12; ++x) cd[x] = cil[x] - cj[x];
            #pragma unroll
            for (int e = 0; e < 8; ++e) {
                const int k = g * 8 + e;
                float v = 0.f;
                if (k < 16) {
                    const int mm = k >> 2, pp = k & 3;
                    v = (cd[mm*3+0]*cd[pp*3+0] + cd[mm*3+1]*cd[pp*3+1] + cd[mm*3+2]*cd[pp*3+2]) * rnl[k];
                }
                radB[e] = (__bf16)v;
            }
        }

        // GEMM1: K=224 (hj 128 from LDS A-frags, z 64 from global A-frags, rad 32 from LDS)
        f32x4 a1[8];
        #pragma unroll
        for (int rf = 0; rf < 8; ++rf) a1[rf] = (f32x4){0.f, 0.f, 0.f, 0.f};

        #pragma unroll
        for (int kk = 0; kk < 4; ++kk) {
            const bf16x8 bf = cvt8(hrow + kk * 32 + g * 8);
            #pragma unroll
            for (int rf = 0; rf < 8; ++rf)
                a1[rf] = __builtin_amdgcn_mfma_f32_16x16x32_bf16(
                    *reinterpret_cast<const bf16x8*>(A1 + ((kk * 8 + rf) * 64 + l) * 8), bf, a1[rf], 0, 0, 0);
        }
        #pragma unroll
        for (int kk = 0; kk < 2; ++kk) {
            const bf16x8 bf = cvt8(zrow + kk * 32 + g * 8);
            #pragma unroll
            for (int rf = 0; rf < 8; ++rf)
                a1[rf] = __builtin_amdgcn_mfma_f32_16x16x32_bf16(
                    *reinterpret_cast<const bf16x8*>(wsMsgA + 20480 + ((kk * 8 + rf) * 64 + l) * 8), bf, a1[rf], 0, 0, 0);
        }
        #pragma unroll
        for (int rf = 0; rf < 8; ++rf)
            a1[rf] = __builtin_amdgcn_mfma_f32_16x16x32_bf16(
                *reinterpret_cast<const bf16x8*>(A1 + 16384 + (rf * 64 + l) * 8), radB, a1[rf], 0, 0, 0);

        // hidden = silu(acc + hA[c]) -> bf16 into this lane's hidm row
        #pragma unroll
        for (int rf = 0; rf < 8; ++rf) {
            const int cb = rf * 16 + g * 4;
            union { __bf16 b4[4]; unsigned long long u; } pk;
            #pragma unroll
            for (int r = 0; r < 4; ++r) pk.b4[r] = (__bf16)silu(a1[rf][r] + hAl[cb + r]);
            *reinterpret_cast<unsigned long long*>(hidm + rb + cb) = pk.u;
        }
        __builtin_amdgcn_wave_barrier();

        // GEMM2: m^T = W2^T x hidden^T (W2 A-frags from global/L2)
        f32x4 a2[8];
        #pragma unroll
        for (int rf = 0; rf < 8; ++rf) a2[rf] = (f32x4){0.f, 0.f, 0.f, 0.f};
        #pragma unroll
        for (int kk2 = 0; kk2 < 4; ++kk2) {
            const bf16x8 bf2 = *reinterpret_cast<const bf16x8*>(hidm + rb + kk2 * 32 + g * 8);
            #pragma unroll
            for (int rf = 0; rf < 8; ++rf)
                a2[rf] = __builtin_amdgcn_mfma_f32_16x16x32_bf16(
                    *reinterpret_cast<const bf16x8*>(wsW2A + ((kk2 * 8 + rf) * 64 + l) * 8), bf2, a2[rf], 0, 0, 0);
        }
        __builtin_amdgcn_wave_barrier();

        // epilogue: +b2, agg accumulate, pack m (bf16) over the hidm row
        const float wI = iml[j], wE = eml[j];
        #pragma unroll
        for (int rf = 0; rf < 8; ++rf) {
            const int cb = rf * 16 + g * 4;
            union { __bf16 b4[4]; unsigned long long u; } pk;
            #pragma unroll
            for (int r = 0; r < 4; ++r) {
                const float mval = a2[rf][r] + b2l[cb + r];
                aI[rf * 4 + r] += mval * wI;
                aE[rf * 4 + r] += mval * wE;
                pk.b4[r] = (__bf16)mval;
            }
            *reinterpret_cast<unsigned long long*>(hidm + rb + cb) = pk.u;
        }
        __builtin_amdgcn_wave_barrier();

        // flush this wave's 16 rows -> m_out (coalesced: 16 lanes x 16B per row)
        #pragma unroll
        for (int it = 0; it < 4; ++it) {
            const int c2 = it * 64 + l;
            const int rl = c2 >> 4, oct = c2 & 15;
            const uint4 v = *reinterpret_cast<const uint4*>(hidm + (size_t)(w * 16 + rl) * 136 + oct * 8);
            *reinterpret_cast<uint4*>(m_out + ((size_t)(bi * 256 + w * 32 + cf * 16 + rl)) * 128 + oct * 8) = v;
        }
        __builtin_amdgcn_wave_barrier();
    }

    __syncthreads();   // all waves done with hidm -> safe to alias reduction buffers

    #pragma unroll
    for (int s = 1; s < 16; s <<= 1) {
        #pragma unroll
        for (int i2 = 0; i2 < 32; ++i2) {
            aI[i2] += __shfl_xor(aI[i2], s, 64);
            aE[i2] += __shfl_xor(aE[i2], s, 64);
        }
    }
    float* redf = reinterpret_cast<float*>(hidm);   // redI: [0,1024), redE: [1024,2048) floats
    if (l15 == 0) {
        #pragma unroll
        for (int rf = 0; rf < 8; ++rf)
            #pragma unroll
            for (int r = 0; r < 4; ++r) {
                const int c = rf * 16 + g * 4 + r;
                redf[w * 128 + c]        = aI[rf * 4 + r];
                redf[1024 + w * 128 + c] = aE[rf * 4 + r];
            }
    }
    __syncthreads();
    if (t < 128) {
        float sI = 0.f, sE = 0.f;
        #pragma unroll
        for (int w8 = 0; w8 < 8; ++w8) { sI += redf[w8 * 128 + t]; sE += redf[1024 + w8 * 128 + t]; }
        aggI[bi * 128 + t] = sI;
        aggE[bi * 128 + t] = sE;
    }
}

// ---------------- pack coord weights into A-fragment order (once) ----------------
__global__ __launch_bounds__(256) void k_pack_coord_w(const float* __restrict__ c0w1,
                                                      const float* __restrict__ c1w1,
                                                      unsigned short* __restrict__ wsA)
{
    const int o = blockIdx.x * 256 + threadIdx.x;    // < 32768
    const int p  = o >> 14;
    const int r  = o & 16383;
    const int jj = r & 7, l = (r >> 3) & 63, rf = (r >> 9) & 7, kk = r >> 12;
    const int k = kk * 32 + ((l >> 4) << 3) + jj;
    const int c = (rf << 4) + (l & 15);
    const float* W = p ? c1w1 : c0w1;
    wsA[o] = f2bf(W[k * 128 + c]);
}

// ---------------- coord update via MFMA ----------------
__global__ __launch_bounds__(512) void k_coord_mfma(
    const float* __restrict__ coord,
    const unsigned short* __restrict__ m_in,
    const float* __restrict__ intra, const float* __restrict__ inter,
    const unsigned short* __restrict__ wsA,
    const float* __restrict__ c0w2, const float* __restrict__ c1w2,
    float* __restrict__ coord_out)
{
    const int bi = blockIdx.x;
    const int b  = bi >> 8;
    const int t  = threadIdx.x;
    const int w  = t >> 6;
    const int l  = t & 63;
    const int g  = l >> 4;
    const int l15 = l & 15;

    __shared__ __align__(16) unsigned short Apk[2 * 16384];
    __shared__ __align__(16) float W2l[2 * 128 * 4];
    __shared__ float iml[256], eml[256];
    __shared__ float cil[12];
    __shared__ float redC[8][12];
    __shared__ float redD[8];

    {
        const float4* srcA = reinterpret_cast<const float4*>(wsA);
        float4* dstA = reinterpret_cast<float4*>(Apk);
        for (int idx = t; idx < 4096; idx += 512) dstA[idx] = srcA[idx];
        if (t < 512) { W2l[t] = c0w2[t]; W2l[512 + t] = c1w2[t]; }
        if (t < 256) { iml[t] = intra[bi * 256 + t]; eml[t] = inter[bi * 256 + t]; }
        if (t < 12)  cil[t] = coord[bi * 12 + t];
    }
    __syncthreads();

    f32x4 acc[2][2][8];
    #pragma unroll
    for (int p = 0; p < 2; ++p)
        #pragma unroll
        for (int cf = 0; cf < 2; ++cf)
            #pragma unroll
            for (int rf = 0; rf < 8; ++rf)
                acc[p][cf][rf] = (f32x4){0.f, 0.f, 0.f, 0.f};

    #pragma unroll
    for (int kk = 0; kk < 4; ++kk) {
        bf16x8 bfr[2];
        #pragma unroll
        for (int cf = 0; cf < 2; ++cf) {
            const size_t mo = ((size_t)(bi * 256 + w * 32 + cf * 16 + l15)) * 128 + kk * 32 + g * 8;
            bfr[cf] = *reinterpret_cast<const bf16x8*>(m_in + mo);
        }
        #pragma unroll
        for (int rf = 0; rf < 8; ++rf) {
            const bf16x8 a0 = *reinterpret_cast<const bf16x8*>(Apk + ((kk * 8 + rf) * 64 + l) * 8);
            const bf16x8 a1 = *reinterpret_cast<const bf16x8*>(Apk + 16384 + ((kk * 8 + rf) * 64 + l) * 8);
            acc[0][0][rf] = __builtin_amdgcn_mfma_f32_16x16x32_bf16(a0, bfr[0], acc[0][0][rf], 0, 0, 0);
            acc[0][1][rf] = __builtin_amdgcn_mfma_f32_16x16x32_bf16(a0, bfr[1], acc[0][1][rf], 0, 0, 0);
            acc[1][0][rf] = __builtin_amdgcn_mfma_f32_16x16x32_bf16(a1, bfr[0], acc[1][0][rf], 0, 0, 0);
            acc[1][1][rf] = __builtin_amdgcn_mfma_f32_16x16x32_bf16(a1, bfr[1], acc[1][1][rf], 0, 0, 0);
        }
    }

    float wf[2][2][4];
    #pragma unroll
    for (int p = 0; p < 2; ++p)
        #pragma unroll
        for (int cf = 0; cf < 2; ++cf)
            #pragma unroll
            for (int pc = 0; pc < 4; ++pc) wf[p][cf][pc] = 0.f;

    #pragma unroll
    for (int p = 0; p < 2; ++p)
        #pragma unroll
        for (int rf = 0; rf < 8; ++rf)
            #pragma unroll
            for (int r = 0; r < 4; ++r) {
                const int c = rf * 16 + g * 4 + r;
                const float4 w2 = *reinterpret_cast<const float4*>(&W2l[(p * 128 + c) * 4]);
                #pragma unroll
                for (int cf = 0; cf < 2; ++cf) {
                    const float hid = silu(acc[p][cf][rf][r]);
                    wf[p][cf][0] += hid * w2.x;
                    wf[p][cf][1] += hid * w2.y;
                    wf[p][cf][2] += hid * w2.z;
                    wf[p][cf][3] += hid * w2.w;
                }
            }

    float accC[12];
    #pragma unroll
    for (int q2 = 0; q2 < 12; ++q2) accC[q2] = 0.f;
    float dacc = 0.f;

    #pragma unroll
    for (int cf = 0; cf < 2; ++cf) {
        float w0c[4], w1c[4];
        #pragma unroll
        for (int pc = 0; pc < 4; ++pc) { w0c[pc] = wf[0][cf][pc]; w1c[pc] = wf[1][cf][pc]; }
        #pragma unroll
        for (int pc = 0; pc < 4; ++pc) {
            w0c[pc] += __shfl_xor(w0c[pc], 16, 64); w0c[pc] += __shfl_xor(w0c[pc], 32, 64);
            w1c[pc] += __shfl_xor(w1c[pc], 16, 64); w1c[pc] += __shfl_xor(w1c[pc], 32, 64);
        }
        const int j = w * 32 + cf * 16 + l15;
        const float im = iml[j], em = eml[j];
        float wt[4];
        #pragma unroll
        for (int pc = 0; pc < 4; ++pc) wt[pc] = w0c[pc] * im + w1c[pc] * em;
        const float* cjp = coord + (size_t)(b * 256 + j) * 12;
        const float4 cj0 = *reinterpret_cast<const float4*>(cjp);
        const float4 cj1 = *reinterpret_cast<const float4*>(cjp + 4);
        const float4 cj2 = *reinterpret_cast<const float4*>(cjp + 8);
        accC[0]  += (cil[0]  - cj0.x) * wt[0];
        accC[1]  += (cil[1]  - cj0.y) * wt[0];
        accC[2]  += (cil[2]  - cj0.z) * wt[0];
        accC[3]  += (cil[3]  - cj0.w) * wt[1];
        accC[4]  += (cil[4]  - cj1.x) * wt[1];
        accC[5]  += (cil[5]  - cj1.y) * wt[1];
        accC[6]  += (cil[6]  - cj1.z) * wt[2];
        accC[7]  += (cil[7]  - cj1.w) * wt[2];
        accC[8]  += (cil[8]  - cj2.x) * wt[2];
        accC[9]  += (cil[9]  - cj2.y) * wt[3];
        accC[10] += (cil[10] - cj2.z) * wt[3];
        accC[11] += (cil[11] - cj2.w) * wt[3];
        dacc += im + em;
    }
    #pragma unroll
    for (int s = 1; s < 16; s <<= 1) {
        #pragma unroll
        for (int q2 = 0; q2 < 12; ++q2) accC[q2] += __shfl_xor(accC[q2], s, 64);
        dacc += __shfl_xor(dacc, s, 64);
    }
    if (l == 0) {
        #pragma unroll
        for (int q2 = 0; q2 < 12; ++q2) redC[w][q2] = accC[q2];
        redD[w] = dacc;
    }
    __syncthreads();
    if (t < 12) {
        float s = 0.f, d = 0.f;
        #pragma unroll
        for (int ww = 0; ww < 8; ++ww) { s += redC[ww][t]; d += redD[ww]; }
        d += 2.56e-4f;   // L * 1e-6
        coord_out[bi * 12 + t] = coord[bi * 12 + t] + s / d;
    }
}

// ---------------- node update + LayerNorm ----------------
__global__ __launch_bounds__(128) void k_node(
    const float* __restrict__ h,
    const float* __restrict__ aggI, const float* __restrict__ aggE,
    const float* __restrict__ rel0, const float* __restrict__ rel1,
    const float* __restrict__ nw1, const float* __restrict__ nb1,
    const float* __restrict__ nw2, const float* __restrict__ nb2,
    const float* __restrict__ lnw, const float* __restrict__ lnb,
    float* __restrict__ h_out)
{
    const int r = blockIdx.x, t = threadIdx.x;
    __shared__ float hl[128], aIl[128], aEl[128], a0l[128], a1l[128], hidl[128];
    hl[t]  = h[r * 128 + t];
    aIl[t] = aggI[r * 128 + t];
    aEl[t] = aggE[r * 128 + t];
    __syncthreads();
    float a0 = 0.f, a1 = 0.f;
    #pragma unroll 8
    for (int k = 0; k < 128; ++k) { a0 += aIl[k] * rel0[k * 128 + t]; a1 += aEl[k] * rel1[k * 128 + t]; }
    a0l[t] = a0; a1l[t] = a1;
    __syncthreads();
    float pre = nb1[t];
    #pragma unroll 8
    for (int k = 0; k < 128; ++k) pre += hl[k]  * nw1[k * 128 + t];
    #pragma unroll 8
    for (int k = 0; k < 128; ++k) pre += a0l[k] * nw1[(128 + k) * 128 + t];
    #pragma unroll 8
    for (int k = 0; k < 128; ++k) pre += a1l[k] * nw1[(256 + k) * 128 + t];
    hidl[t] = silu(pre);
    __syncthreads();
    float upd = nb2[t];
    #pragma unroll 8
    for (int k = 0; k < 128; ++k) upd += hidl[k] * nw2[k * 128 + t];
    const float x = hl[t] + upd;
    float s = x, s2 = x * x;
    #pragma unroll
    for (int d = 1; d < 64; d <<= 1) { s += __shfl_xor(s, d, 64); s2 += __shfl_xor(s2, d, 64); }
    __shared__ float rs[2], rs2[2];
    const int wv = t >> 6;
    if ((t & 63) == 0) { rs[wv] = s; rs2[wv] = s2; }
    __syncthreads();
    const float S = rs[0] + rs[1], S2 = rs2[0] + rs2[1];
    const float mu = S * (1.f / 128.f);
    const float var = S2 * (1.f / 128.f) - mu * mu;
    h_out[r * 128 + t] = (x - mu) * rsqrtf(var + 1e-5f) * lnw[t] + lnb[t];
}

// ---------------- edge update via MFMA ----------------
__global__ __launch_bounds__(512) void k_edge_mfma(
    const float* __restrict__ z,
    const float* __restrict__ eA, const float* __restrict__ eB,
    const unsigned short* __restrict__ wE1A,
    const unsigned short* __restrict__ wEW2A,
    const float* __restrict__ eb2,
    float* __restrict__ z_out)
{
    const int bi = blockIdx.x;
    const int b  = bi >> 8;
    const int t  = threadIdx.x;
    const int w  = t >> 6, l = t & 63, g = l >> 4, l15 = l & 15;

    __shared__ __align__(16) unsigned short hidm[256 * 136];  // rows reused fp32 for z_new
    __shared__ float eAl[128];
    __shared__ float eb2l[64];

    if (t < 128)      eAl[t] = eA[bi * 128 + t];
    else if (t < 192) eb2l[t - 128] = eb2[t - 128];
    __syncthreads();

    #pragma unroll 1
    for (int cf = 0; cf < 2; ++cf) {
        asm volatile("" ::: "memory");
        const int j = w * 32 + cf * 16 + l15;
        const float* zrow = z + (size_t)(bi * 256 + j) * 64;

        f32x4 a1[8];
        #pragma unroll
        for (int rf = 0; rf < 8; ++rf) a1[rf] = (f32x4){0.f, 0.f, 0.f, 0.f};
        #pragma unroll
        for (int kk = 0; kk < 2; ++kk) {
            const bf16x8 bf = cvt8(zrow + kk * 32 + g * 8);
            #pragma unroll
            for (int rf = 0; rf < 8; ++rf)
                a1[rf] = __builtin_amdgcn_mfma_f32_16x16x32_bf16(
                    *reinterpret_cast<const bf16x8*>(wE1A + ((kk * 8 + rf) * 64 + l) * 8), bf, a1[rf], 0, 0, 0);
        }

        const float* eBrow = eB + (size_t)(b * 256 + j) * 128;
        #pragma unroll
        for (int rf = 0; rf < 8; ++rf) {
            const int cb = rf * 16 + g * 4;
            const float4 e4 = *reinterpret_cast<const float4*>(eBrow + cb);
            union { __bf16 b4[4]; unsigned long long u; } pk;
            pk.b4[0] = (__bf16)silu(a1[rf][0] + eAl[cb + 0] + e4.x);
            pk.b4[1] = (__bf16)silu(a1[rf][1] + eAl[cb + 1] + e4.y);
            pk.b4[2] = (__bf16)silu(a1[rf][2] + eAl[cb + 2] + e4.z);
            pk.b4[3] = (__bf16)silu(a1[rf][3] + eAl[cb + 3] + e4.w);
            *reinterpret_cast<unsigned long long*>(hidm + (size_t)j * 136 + cb) = pk.u;
        }
        __builtin_amdgcn_wave_barrier();

        f32x4 a2[4];
        #pragma unroll
        for (int rf = 0; rf < 4; ++rf) a2[rf] = (f32x4){0.f, 0.f, 0.f, 0.f};
        #pragma unroll
        for (int kk2 = 0; kk2 < 4; ++kk2) {
            const bf16x8 bf2 = *reinterpret_cast<const bf16x8*>(hidm + (size_t)j * 136 + kk2 * 32 + g * 8);
            #pragma unroll
            for (int rf = 0; rf < 4; ++rf)
                a2[rf] = __builtin_amdgcn_mfma_f32_16x16x32_bf16(
                    *reinterpret_cast<const bf16x8*>(wEW2A + ((kk2 * 4 + rf) * 64 + l) * 8), bf2, a2[rf], 0, 0, 0);
        }
        __builtin_amdgcn_wave_barrier();

        float* zst = reinterpret_cast<float*>(hidm + (size_t)j * 136);
        #pragma unroll
        for (int rf = 0; rf < 4; ++rf) {
            const int p0 = rf * 16 + g * 4;
            float4 v;
            v.x = a2[rf][0] + eb2l[p0 + 0];
            v.y = a2[rf][1] + eb2l[p0 + 1];
            v.z = a2[rf][2] + eb2l[p0 + 2];
            v.w = a2[rf][3] + eb2l[p0 + 3];
            *reinterpret_cast<float4*>(zst + p0) = v;
        }
        __builtin_amdgcn_wave_barrier();
    }

    #pragma unroll
    for (int it = 0; it < 8; ++it) {
        const int chunk = it * 64 + l;
        const int jl = chunk >> 4, oct = chunk & 15;
        const int jr = w * 32 + jl;
        const float4 v = *reinterpret_cast<const float4*>(
            reinterpret_cast<const float*>(hidm + (size_t)jr * 136) + oct * 4);
        *reinterpret_cast<float4*>(z_out + (size_t)(bi * 256 + jr) * 64 + oct * 4) = v;
    }
}

extern "C" void kernel_launch(void* const* d_in, const int* in_sizes, int n_in,
                              void* d_out, int out_size, void* d_ws, size_t ws_size,
                              hipStream_t stream)
{
    (void)in_sizes; (void)n_in; (void)out_size; (void)ws_size;
    const float* coord  = (const float*)d_in[2];
    const float* h      = (const float*)d_in[3];
    const float* z      = (const float*)d_in[4];
    const float* intra  = (const float*)d_in[5];
    const float* inter  = (const float*)d_in[6];
    const float* msg_w1 = (const float*)d_in[7];
    const float* msg_b1 = (const float*)d_in[8];
    const float* msg_w2 = (const float*)d_in[9];
    const float* msg_b2 = (const float*)d_in[10];
    const float* rel_w0 = (const float*)d_in[11];
    const float* rel_w1 = (const float*)d_in[12];
    const float* node_w1= (const float*)d_in[13];
    const float* node_b1= (const float*)d_in[14];
    const float* node_w2= (const float*)d_in[15];
    const float* node_b2= (const float*)d_in[16];
    const float* edge_w1= (const float*)d_in[17];
    const float* edge_b1= (const float*)d_in[18];
    const float* edge_w2= (const float*)d_in[19];
    const float* edge_b2= (const float*)d_in[20];
    const float* c0w1   = (const float*)d_in[21];
    const float* c0w2   = (const float*)d_in[23];
    const float* c1w1   = (const float*)d_in[24];
    const float* c1w2   = (const float*)d_in[26];
    const float* lnw    = (const float*)d_in[27];
    const float* lnb    = (const float*)d_in[28];

    float* out       = (float*)d_out;
    float* coord_out = out;                       // [N,L,C,3]   12288
    float* h_out     = out + 12288;               // [N,L,D]     131072
    float* z_out     = out + 12288 + 131072;      // [N,L,L,P]   16777216

    float* ws      = (float*)d_ws;
    float* partial = ws;                          // 16384
    float* rnorm   = ws + 16384;
    float* hA      = ws + 16448;                  // 131072
    float* hB      = hA + 131072;                 // (unused, layout kept)
    float* aggI    = hB + 131072;
    float* aggE    = aggI + 131072;
    float* eA      = aggE + 131072;
    float* eB      = eA + 131072;
    unsigned short* wsA    = (unsigned short*)(eB + 131072);  // 32768 us (coord A-frags)
    unsigned short* wsMsgA = wsA + 32768;                     // 28672 us (msg GEMM1 A-frags)
    unsigned short* wsW2A  = wsMsgA + 28672;                  // 16384 us (msg W2 A-frags)
    unsigned short* wsE1A  = wsW2A + 16384;                   //  8192 us (edge GEMM1 A-frags)
    unsigned short* wsEW2A = wsE1A + 8192;                    //  8192 us (edge W2 A-frags)
    // m (bf16) lives in the z_new output region (67 MB exact fit, consumed before k_edge).
    unsigned short* m_bf = (unsigned short*)z_out;

    k_norm_partial<<<1024, 256, 0, stream>>>(coord, partial);
    k_norm_finish<<<1, 256, 0, stream>>>(partial, rnorm);
    k_pack_coord_w<<<128, 256, 0, stream>>>(c0w1, c1w1, wsA);
    k_pack_msg_w<<<176, 256, 0, stream>>>(msg_w1, msg_w2, wsMsgA, wsW2A);
    k_pack_edge_w<<<64, 256, 0, stream>>>(edge_w1, edge_w2, wsE1A, wsEW2A);
    k_pre_hA<<<1024, 128, 0, stream>>>(h, msg_w1, msg_b1, hA);
    k_msg_mfma<<<1024, 512, 0, stream>>>(coord, h, z, intra, inter, hA,
                                         wsMsgA, wsW2A, msg_b2, rnorm,
                                         m_bf, aggI, aggE);
    k_coord_mfma<<<1024, 512, 0, stream>>>(coord, m_bf, intra, inter, wsA,
                                           c0w2, c1w2, coord_out);
    k_node<<<1024, 128, 0, stream>>>(h, aggI, aggE, rel_w0, rel_w1,
                                     node_w1, node_b1, node_w2, node_b2, lnw, lnb, h_out);
    k_pre_msg<<<1024, 256, 0, stream>>>(h_out, edge_w1, edge_b1, eA, eB);
    k_edge_mfma<<<1024, 512, 0, stream>>>(z, eA, eB, wsE1A, wsEW2A, edge_b2, z_out);
}

// Round 8
// 281.702 us; speedup vs baseline: 2.0275x; 1.2742x over previous
//
#include <hip/hip_runtime.h>

// SABlock: EGNN-style block. N=4, L=256, D=128, P=64, C=4.
//   k_norm_partial/k_norm_finish : global L2 norm of radial -> rnorm[16]
//   k_pack_coord_w : pre-pack c0w1/c1w1 into MFMA A-frag order (bf16), once
//   k_pack_msg_w   : pre-pack msg_w1 A-frags (hj LDS-part | rad LDS-part | z global-part) + msg_w2
//   k_pack_edge_w  : pre-pack edge_w1 z-rows (K=64) and edge_w2 A-frags
//   k_pre_hA   : hA = h@msg_w1[0:128]+msg_b1
//   k_msg_mfma : GEMM1 (K=224) -> silu -> GEMM2 -> m bf16
//                v4: NO in-kernel aggregates (R7: 64 persistent agg VGPRs + the
//                compiler's 128-VGPR cap for 2 blocks/CU => spills, 300MB traffic)
//   k_agg      : aggI/aggE from m_bf (memory-bound, coalesced, ~11us)
//   k_coord_mfma : coord MLPs on MFMA + coord update epilogue
//   k_node     : node MLP + LayerNorm
//   k_pre_msg  : eA/eB for edge path (uses h_new)
//   k_edge_mfma : GEMM1 (K=64, z) -> silu(+eA+eB) -> GEMM2 (K=128) -> z_new fp32

#define DEV static __device__ __forceinline__

DEV float silu(float x) { return x / (1.0f + __expf(-x)); }

DEV float bf2f(unsigned short u) {
    unsigned int v = ((unsigned int)u) << 16;
    float f;
    __builtin_memcpy(&f, &v, 4);
    return f;
}
DEV unsigned short f2bf(float f) {
    unsigned int x;
    __builtin_memcpy(&x, &f, 4);
    x += 0x7fffu + ((x >> 16) & 1u);
    return (unsigned short)(x >> 16);
}

struct __align__(8) US4 { unsigned short x, y, z, w; };

typedef __bf16 bf16x8 __attribute__((ext_vector_type(8)));
typedef float  f32x4  __attribute__((ext_vector_type(4)));

#define FMA4(acc_, s_, v_) { (acc_).x += (s_)*(v_).x; (acc_).y += (s_)*(v_).y; (acc_).z += (s_)*(v_).z; (acc_).w += (s_)*(v_).w; }

DEV bf16x8 cvt8(const float* p) {
    const float4 a = *reinterpret_cast<const float4*>(p);
    const float4 c = *reinterpret_cast<const float4*>(p + 4);
    bf16x8 r;
    r[0] = (__bf16)a.x; r[1] = (__bf16)a.y; r[2] = (__bf16)a.z; r[3] = (__bf16)a.w;
    r[4] = (__bf16)c.x; r[5] = (__bf16)c.y; r[6] = (__bf16)c.z; r[7] = (__bf16)c.w;
    return r;
}

// ---------------- norm of radial ----------------
__global__ __launch_bounds__(256) void k_norm_partial(const float* __restrict__ coord,
                                                      float* __restrict__ partial)
{
    const int t = threadIdx.x;
    const int r = blockIdx.x * 256 + t;
    const int b = r >> 16, rem = r & 0xFFFF, i = rem >> 8, j = rem & 255;
    const float* ci = coord + (b * 256 + i) * 12;
    const float* cj = coord + (b * 256 + j) * 12;
    float cd[4][3];
    #pragma unroll
    for (int c = 0; c < 4; ++c)
        #pragma unroll
        for (int x = 0; x < 3; ++x)
            cd[c][x] = ci[c * 3 + x] - cj[c * 3 + x];
    float sq[16];
    #pragma unroll
    for (int m = 0; m < 4; ++m)
        #pragma unroll
        for (int p = 0; p < 4; ++p) {
            float v = cd[m][0] * cd[p][0] + cd[m][1] * cd[p][1] + cd[m][2] * cd[p][2];
            sq[m * 4 + p] = v * v;
        }
    #pragma unroll
    for (int s = 1; s < 64; s <<= 1)
        #pragma unroll
        for (int qq = 0; qq < 16; ++qq)
            sq[qq] += __shfl_xor(sq[qq], s, 64);
    __shared__ float red[4][16];
    const int wave = t >> 6, lane = t & 63;
    if (lane == 0)
        #pragma unroll
        for (int qq = 0; qq < 16; ++qq) red[wave][qq] = sq[qq];
    __syncthreads();
    if (t < 16)
        partial[blockIdx.x * 16 + t] = red[0][t] + red[1][t] + red[2][t] + red[3][t];
}

__global__ __launch_bounds__(256) void k_norm_finish(const float* __restrict__ partial,
                                                     float* __restrict__ rnorm)
{
    const int t = threadIdx.x;
    const int cc = t & 15, g = t >> 4;
    float s = 0.f;
    for (int k = 0; k < 64; ++k) s += partial[(g * 64 + k) * 16 + cc];
    __shared__ float red[16][17];
    red[g][cc] = s;
    __syncthreads();
    if (t < 16) {
        float tot = 0.f;
        #pragma unroll
        for (int gg = 0; gg < 16; ++gg) tot += red[gg][t];
        rnorm[t] = 1.0f / fmaxf(sqrtf(tot), 1e-12f);
    }
}

// ---------------- hA only (msg path) ----------------
__global__ __launch_bounds__(128) void k_pre_hA(const float* __restrict__ h,
                                                const float* __restrict__ w1,
                                                const float* __restrict__ b1,
                                                float* __restrict__ hA)
{
    const int r = blockIdx.x;
    const int t = threadIdx.x;
    __shared__ float hl[128];
    hl[t] = h[r * 128 + t];
    __syncthreads();
    float acc = b1[t];
    #pragma unroll 8
    for (int k = 0; k < 128; ++k) acc += hl[k] * w1[k * 128 + t];
    hA[r * 128 + t] = acc;
}

// ---------------- row-precompute for edge path ----------------
__global__ __launch_bounds__(256) void k_pre_msg(const float* __restrict__ h,
                                                 const float* __restrict__ w1,
                                                 const float* __restrict__ b1,
                                                 float* __restrict__ hA,
                                                 float* __restrict__ hB)
{
    const int r = blockIdx.x;
    const int t = threadIdx.x;
    const int half = t >> 7, c = t & 127;
    __shared__ float hl[128];
    if (t < 128) hl[t] = h[r * 128 + t];
    __syncthreads();
    const float* W = w1 + half * 128 * 128;
    float acc = half ? 0.f : b1[c];
    #pragma unroll 8
    for (int k = 0; k < 128; ++k) acc += hl[k] * W[k * 128 + c];
    (half ? hB : hA)[r * 128 + c] = acc;
}

// ---------------- pack msg weights into A-frag order (once) ----------------
// Layout (shorts):
//  [0,16384)      hj frags   kk0..3, rf0..7 : k=kk*32+(l>>4)*8+jj, src row 128+k   (LDS-staged)
//  [16384,20480)  rad frags  rf0..7         : k=(l>>4)*8+jj, src row 256+k if k<16 else 0 (LDS-staged)
//  [20480,28672)  z frags    kk0..1, rf0..7 : k=kk*32+(l>>4)*8+jj, src row 272+k   (global-read)
// wsW2A unchanged.
__global__ __launch_bounds__(256) void k_pack_msg_w(const float* __restrict__ msg_w1,
                                                    const float* __restrict__ msg_w2,
                                                    unsigned short* __restrict__ wsMsgA,
                                                    unsigned short* __restrict__ wsW2A)
{
    const int o = blockIdx.x * 256 + threadIdx.x;    // < 45056
    if (o < 16384) {
        const int jj = o & 7, l = (o >> 3) & 63, rf = (o >> 9) & 7, kk = o >> 12;
        const int k = kk * 32 + ((l >> 4) << 3) + jj;
        const int c = (rf << 4) + (l & 15);
        wsMsgA[o] = f2bf(msg_w1[(128 + k) * 128 + c]);
    } else if (o < 20480) {
        const int o2 = o - 16384;
        const int jj = o2 & 7, l = (o2 >> 3) & 63, rf = (o2 >> 9) & 7;
        const int k = ((l >> 4) << 3) + jj;
        const int c = (rf << 4) + (l & 15);
        wsMsgA[o] = (k < 16) ? f2bf(msg_w1[(256 + k) * 128 + c]) : (unsigned short)0;
    } else if (o < 28672) {
        const int o3 = o - 20480;
        const int jj = o3 & 7, l = (o3 >> 3) & 63, rf = (o3 >> 9) & 7, kk = o3 >> 12;
        const int k = kk * 32 + ((l >> 4) << 3) + jj;
        const int c = (rf << 4) + (l & 15);
        wsMsgA[o] = f2bf(msg_w1[(272 + k) * 128 + c]);
    } else {
        const int o2 = o - 28672;                     // < 16384
        const int jj = o2 & 7, l = (o2 >> 3) & 63, rf = (o2 >> 9) & 7, kk2 = o2 >> 12;
        const int c  = kk2 * 32 + ((l >> 4) << 3) + jj;
        const int c2 = (rf << 4) + (l & 15);
        wsW2A[o2] = f2bf(msg_w2[c * 128 + c2]);
    }
}

// ---------------- pack edge weights into A-frag order (once) ----------------
__global__ __launch_bounds__(256) void k_pack_edge_w(const float* __restrict__ edge_w1,
                                                     const float* __restrict__ edge_w2,
                                                     unsigned short* __restrict__ wE1A,
                                                     unsigned short* __restrict__ wEW2A)
{
    const int o = blockIdx.x * 256 + threadIdx.x;    // < 16384
    if (o < 8192) {
        const int jj = o & 7, l = (o >> 3) & 63, rf = (o >> 9) & 7, kk = o >> 12;
        const int k = kk * 32 + ((l >> 4) << 3) + jj;
        const int c = (rf << 4) + (l & 15);
        wE1A[o] = f2bf(edge_w1[(256 + k) * 128 + c]);
    } else {
        const int o2 = o - 8192;
        const int jj = o2 & 7, l = (o2 >> 3) & 63, rf = (o2 >> 9) & 3, kk2 = o2 >> 11;
        const int k = kk2 * 32 + ((l >> 4) << 3) + jj;
        const int p = (rf << 4) + (l & 15);
        wEW2A[o2] = f2bf(edge_w2[k * 64 + p]);
    }
}

// ---------------- message MLP via MFMA (v4: no in-kernel aggregates) ----------------
__global__ __launch_bounds__(512) void k_msg_mfma(
    const float* __restrict__ coord, const float* __restrict__ h,
    const float* __restrict__ z,
    const float* __restrict__ hA,
    const unsigned short* __restrict__ wsMsgA,
    const unsigned short* __restrict__ wsW2A,
    const float* __restrict__ msg_b2, const float* __restrict__ rnorm,
    unsigned short* __restrict__ m_out)
{
    const int bi = blockIdx.x;
    const int b  = bi >> 8;
    const int t  = threadIdx.x;
    const int w  = t >> 6, l = t & 63, g = l >> 4, l15 = l & 15;

    __shared__ __align__(16) unsigned short A1[20480];        // 40960 B: hj + rad frags
    __shared__ __align__(16) unsigned short hidm[128 * 136];  // 34816 B: per-phase rows (w*16+l15)
    __shared__ float hAl[128], b2l[128];
    __shared__ float cil[12];
    __shared__ float rnl[16];

    {
        const float4* src = reinterpret_cast<const float4*>(wsMsgA);
        float4* dst = reinterpret_cast<float4*>(A1);
        #pragma unroll
        for (int it = 0; it < 5; ++it) dst[it * 512 + t] = src[it * 512 + t];  // 2560 float4 = 40 KB
    }
    if (t < 12) cil[t] = coord[bi * 12 + t];
    if (t < 16) rnl[t] = rnorm[t];
    if (t < 128)      hAl[t] = hA[bi * 128 + t];
    else if (t < 256) b2l[t - 128] = msg_b2[t - 128];
    __syncthreads();

    const int row = w * 16 + l15;          // this lane's hidm row (per-phase)
    const size_t rb = (size_t)row * 136;   // shorts

    #pragma unroll 1
    for (int cf = 0; cf < 2; ++cf) {
        const int j = w * 32 + cf * 16 + l15;
        const float* hrow = h + (size_t)(b * 256 + j) * 128;
        const float* zrow = z + (size_t)(bi * 256 + j) * 64;

        // rad B-frag inline (K=32 slot: k = g*8+e, real for k<16, zero-padded above)
        bf16x8 radB;
        {
            const float* cj = coord + (size_t)(b * 256 + j) * 12;
            float cd[12];
            #pragma unroll
            for (int x = 0; x < 12; ++x) cd[x] = cil[x] - cj[x];
            #pragma unroll
            for (int e = 0; e < 8; ++e) {
                const int k = g * 8 + e;
                float v = 0.f;
                if (k < 16) {
                    const int mm = k >> 2, pp = k & 3;
                    v = (cd[mm*3+0]*cd[pp*3+0] + cd[mm*3+1]*cd[pp*3+1] + cd[mm*3+2]*cd[pp*3+2]) * rnl[k];
                }
                radB[e] = (__bf16)v;
            }
        }

        // GEMM1: K=224 (hj 128 from LDS A-frags, z 64 from global A-frags, rad 32 from LDS)
        f32x4 a1[8];
        #pragma unroll
        for (int rf = 0; rf < 8; ++rf) a1[rf] = (f32x4){0.f, 0.f, 0.f, 0.f};

        #pragma unroll
        for (int kk = 0; kk < 4; ++kk) {
            const bf16x8 bf = cvt8(hrow + kk * 32 + g * 8);
            #pragma unroll
            for (int rf = 0; rf < 8; ++rf)
                a1[rf] = __builtin_amdgcn_mfma_f32_16x16x32_bf16(
                    *reinterpret_cast<const bf16x8*>(A1 + ((kk * 8 + rf) * 64 + l) * 8), bf, a1[rf], 0, 0, 0);
        }
        #pragma unroll
        for (int kk = 0; kk < 2; ++kk) {
            const bf16x8 bf = cvt8(zrow + kk * 32 + g * 8);
            #pragma unroll
            for (int rf = 0; rf < 8; ++rf)
                a1[rf] = __builtin_amdgcn_mfma_f32_16x16x32_bf16(
                    *reinterpret_cast<const bf16x8*>(wsMsgA + 20480 + ((kk * 8 + rf) * 64 + l) * 8), bf, a1[rf], 0, 0, 0);
        }
        #pragma unroll
        for (int rf = 0; rf < 8; ++rf)
            a1[rf] = __builtin_amdgcn_mfma_f32_16x16x32_bf16(
                *reinterpret_cast<const bf16x8*>(A1 + 16384 + (rf * 64 + l) * 8), radB, a1[rf], 0, 0, 0);

        // hidden = silu(acc + hA[c]) -> bf16 into this lane's hidm row
        #pragma unroll
        for (int rf = 0; rf < 8; ++rf) {
            const int cb = rf * 16 + g * 4;
            union { __bf16 b4[4]; unsigned long long u; } pk;
            #pragma unroll
            for (int r = 0; r < 4; ++r) pk.b4[r] = (__bf16)silu(a1[rf][r] + hAl[cb + r]);
            *reinterpret_cast<unsigned long long*>(hidm + rb + cb) = pk.u;
        }
        __builtin_amdgcn_wave_barrier();

        // GEMM2: m^T = W2^T x hidden^T (W2 A-frags from global/L2)
        f32x4 a2[8];
        #pragma unroll
        for (int rf = 0; rf < 8; ++rf) a2[rf] = (f32x4){0.f, 0.f, 0.f, 0.f};
        #pragma unroll
        for (int kk2 = 0; kk2 < 4; ++kk2) {
            const bf16x8 bf2 = *reinterpret_cast<const bf16x8*>(hidm + rb + kk2 * 32 + g * 8);
            #pragma unroll
            for (int rf = 0; rf < 8; ++rf)
                a2[rf] = __builtin_amdgcn_mfma_f32_16x16x32_bf16(
                    *reinterpret_cast<const bf16x8*>(wsW2A + ((kk2 * 8 + rf) * 64 + l) * 8), bf2, a2[rf], 0, 0, 0);
        }
        __builtin_amdgcn_wave_barrier();

        // epilogue: +b2, pack m (bf16) over the hidm row
        #pragma unroll
        for (int rf = 0; rf < 8; ++rf) {
            const int cb = rf * 16 + g * 4;
            union { __bf16 b4[4]; unsigned long long u; } pk;
            #pragma unroll
            for (int r = 0; r < 4; ++r) pk.b4[r] = (__bf16)(a2[rf][r] + b2l[cb + r]);
            *reinterpret_cast<unsigned long long*>(hidm + rb + cb) = pk.u;
        }
        __builtin_amdgcn_wave_barrier();

        // flush this wave's 16 rows -> m_out (coalesced: 16 lanes x 16B per row)
        #pragma unroll
        for (int it = 0; it < 4; ++it) {
            const int c2 = it * 64 + l;
            const int rl = c2 >> 4, oct = c2 & 15;
            const uint4 v = *reinterpret_cast<const uint4*>(hidm + (size_t)(w * 16 + rl) * 136 + oct * 8);
            *reinterpret_cast<uint4*>(m_out + ((size_t)(bi * 256 + w * 32 + cf * 16 + rl)) * 128 + oct * 8) = v;
        }
        __builtin_amdgcn_wave_barrier();
    }
}

// ---------------- masked aggregates from m (memory-bound) ----------------
__global__ __launch_bounds__(256) void k_agg(
    const unsigned short* __restrict__ m_in,
    const float* __restrict__ intra, const float* __restrict__ inter,
    float* __restrict__ aggI, float* __restrict__ aggE)
{
    const int bi = blockIdx.x;
    const int t  = threadIdx.x;
    const int oct = t & 15;        // 8-channel group
    const int jg  = t >> 4;        // 0..15
    __shared__ float iml[256], eml[256];
    __shared__ float red[2][16][128];   // 16 KB
    iml[t] = intra[bi * 256 + t];
    eml[t] = inter[bi * 256 + t];
    __syncthreads();
    float accI[8], accE[8];
    #pragma unroll
    for (int e = 0; e < 8; ++e) { accI[e] = 0.f; accE[e] = 0.f; }
    #pragma unroll 4
    for (int jj = 0; jj < 16; ++jj) {
        const int j = jj * 16 + jg;
        union { uint4 u4; unsigned short us[8]; } v;
        v.u4 = *reinterpret_cast<const uint4*>(m_in + ((size_t)(bi * 256 + j)) * 128 + oct * 8);
        const float wI = iml[j], wE = eml[j];
        #pragma unroll
        for (int e = 0; e < 8; ++e) {
            const float mv = bf2f(v.us[e]);
            accI[e] += mv * wI;
            accE[e] += mv * wE;
        }
    }
    #pragma unroll
    for (int e = 0; e < 8; ++e) {
        red[0][jg][oct * 8 + e] = accI[e];
        red[1][jg][oct * 8 + e] = accE[e];
    }
    __syncthreads();
    if (t < 128) {
        float sI = 0.f, sE = 0.f;
        #pragma unroll
        for (int q = 0; q < 16; ++q) { sI += red[0][q][t]; sE += red[1][q][t]; }
        aggI[bi * 128 + t] = sI;
        aggE[bi * 128 + t] = sE;
    }
}

// ---------------- pack coord weights into A-fragment order (once) ----------------
__global__ __launch_bounds__(256) void k_pack_coord_w(const float* __restrict__ c0w1,
                                                      const float* __restrict__ c1w1,
                                                      unsigned short* __restrict__ wsA)
{
    const int o = blockIdx.x * 256 + threadIdx.x;    // < 32768
    const int p  = o >> 14;
    const int r  = o & 16383;
    const int jj = r & 7, l = (r >> 3) & 63, rf = (r >> 9) & 7, kk = r >> 12;
    const int k = kk * 32 + ((l >> 4) << 3) + jj;
    const int c = (rf << 4) + (l & 15);
    const float* W = p ? c1w1 : c0w1;
    wsA[o] = f2bf(W[k * 128 + c]);
}

// ---------------- coord update via MFMA ----------------
__global__ __launch_bounds__(512) void k_coord_mfma(
    const float* __restrict__ coord,
    const unsigned short* __restrict__ m_in,
    const float* __restrict__ intra, const float* __restrict__ inter,
    const unsigned short* __restrict__ wsA,
    const float* __restrict__ c0w2, const float* __restrict__ c1w2,
    float* __restrict__ coord_out)
{
    const int bi = blockIdx.x;
    const int b  = bi >> 8;
    const int t  = threadIdx.x;
    const int w  = t >> 6;
    const int l  = t & 63;
    const int g  = l >> 4;
    const int l15 = l & 15;

    __shared__ __align__(16) unsigned short Apk[2 * 16384];
    __shared__ __align__(16) float W2l[2 * 128 * 4];
    __shared__ float iml[256], eml[256];
    __shared__ float cil[12];
    __shared__ float redC[8][12];
    __shared__ float redD[8];

    {
        const float4* srcA = reinterpret_cast<const float4*>(wsA);
        float4* dstA = reinterpret_cast<float4*>(Apk);
        for (int idx = t; idx < 4096; idx += 512) dstA[idx] = srcA[idx];
        if (t < 512) { W2l[t] = c0w2[t]; W2l[512 + t] = c1w2[t]; }
        if (t < 256) { iml[t] = intra[bi * 256 + t]; eml[t] = inter[bi * 256 + t]; }
        if (t < 12)  cil[t] = coord[bi * 12 + t];
    }
    __syncthreads();

    f32x4 acc[2][2][8];
    #pragma unroll
    for (int p = 0; p < 2; ++p)
        #pragma unroll
        for (int cf = 0; cf < 2; ++cf)
            #pragma unroll
            for (int rf = 0; rf < 8; ++rf)
                acc[p][cf][rf] = (f32x4){0.f, 0.f, 0.f, 0.f};

    #pragma unroll
    for (int kk = 0; kk < 4; ++kk) {
        bf16x8 bfr[2];
        #pragma unroll
        for (int cf = 0; cf < 2; ++cf) {
            const size_t mo = ((size_t)(bi * 256 + w * 32 + cf * 16 + l15)) * 128 + kk * 32 + g * 8;
            bfr[cf] = *reinterpret_cast<const bf16x8*>(m_in + mo);
        }
        #pragma unroll
        for (int rf = 0; rf < 8; ++rf) {
            const bf16x8 a0 = *reinterpret_cast<const bf16x8*>(Apk + ((kk * 8 + rf) * 64 + l) * 8);
            const bf16x8 a1 = *reinterpret_cast<const bf16x8*>(Apk + 16384 + ((kk * 8 + rf) * 64 + l) * 8);
            acc[0][0][rf] = __builtin_amdgcn_mfma_f32_16x16x32_bf16(a0, bfr[0], acc[0][0][rf], 0, 0, 0);
            acc[0][1][rf] = __builtin_amdgcn_mfma_f32_16x16x32_bf16(a0, bfr[1], acc[0][1][rf], 0, 0, 0);
            acc[1][0][rf] = __builtin_amdgcn_mfma_f32_16x16x32_bf16(a1, bfr[0], acc[1][0][rf], 0, 0, 0);
            acc[1][1][rf] = __builtin_amdgcn_mfma_f32_16x16x32_bf16(a1, bfr[1], acc[1][1][rf], 0, 0, 0);
        }
    }

    float wf[2][2][4];
    #pragma unroll
    for (int p = 0; p < 2; ++p)
        #pragma unroll
        for (int cf = 0; cf < 2; ++cf)
            #pragma unroll
            for (int pc = 0; pc < 4; ++pc) wf[p][cf][pc] = 0.f;

    #pragma unroll
    for (int p = 0; p < 2; ++p)
        #pragma unroll
        for (int rf = 0; rf < 8; ++rf)
            #pragma unroll
            for (int r = 0; r < 4; ++r) {
                const int c = rf * 16 + g * 4 + r;
                const float4 w2 = *reinterpret_cast<const float4*>(&W2l[(p * 128 + c) * 4]);
                #pragma unroll
                for (int cf = 0; cf < 2; ++cf) {
                    const float hid = silu(acc[p][cf][rf][r]);
                    wf[p][cf][0] += hid * w2.x;
                    wf[p][cf][1] += hid * w2.y;
                    wf[p][cf][2] += hid * w2.z;
                    wf[p][cf][3] += hid * w2.w;
                }
            }

    float accC[12];
    #pragma unroll
    for (int q2 = 0; q2 < 12; ++q2) accC[q2] = 0.f;
    float dacc = 0.f;

    #pragma unroll
    for (int cf = 0; cf < 2; ++cf) {
        float w0c[4], w1c[4];
        #pragma unroll
        for (int pc = 0; pc < 4; ++pc) { w0c[pc] = wf[0][cf][pc]; w1c[pc] = wf[1][cf][pc]; }
        #pragma unroll
        for (int pc = 0; pc < 4; ++pc) {
            w0c[pc] += __shfl_xor(w0c[pc], 16, 64); w0c[pc] += __shfl_xor(w0c[pc], 32, 64);
            w1c[pc] += __shfl_xor(w1c[pc], 16, 64); w1c[pc] += __shfl_xor(w1c[pc], 32, 64);
        }
        const int j = w * 32 + cf * 16 + l15;
        const float im = iml[j], em = eml[j];
        float wt[4];
        #pragma unroll
        for (int pc = 0; pc < 4; ++pc) wt[pc] = w0c[pc] * im + w1c[pc] * em;
        const float* cjp = coord + (size_t)(b * 256 + j) * 12;
        const float4 cj0 = *reinterpret_cast<const float4*>(cjp);
        const float4 cj1 = *reinterpret_cast<const float4*>(cjp + 4);
        const float4 cj2 = *reinterpret_cast<const float4*>(cjp + 8);
        accC[0]  += (cil[0]  - cj0.x) * wt[0];
        accC[1]  += (cil[1]  - cj0.y) * wt[0];
        accC[2]  += (cil[2]  - cj0.z) * wt[0];
        accC[3]  += (cil[3]  - cj0.w) * wt[1];
        accC[4]  += (cil[4]  - cj1.x) * wt[1];
        accC[5]  += (cil[5]  - cj1.y) * wt[1];
        accC[6]  += (cil[6]  - cj1.z) * wt[2];
        accC[7]  += (cil[7]  - cj1.w) * wt[2];
        accC[8]  += (cil[8]  - cj2.x) * wt[2];
        accC[9]  += (cil[9]  - cj2.y) * wt[3];
        accC[10] += (cil[10] - cj2.z) * wt[3];
        accC[11] += (cil[11] - cj2.w) * wt[3];
        dacc += im + em;
    }
    #pragma unroll
    for (int s = 1; s < 16; s <<= 1) {
        #pragma unroll
        for (int q2 = 0; q2 < 12; ++q2) accC[q2] += __shfl_xor(accC[q2], s, 64);
        dacc += __shfl_xor(dacc, s, 64);
    }
    if (l == 0) {
        #pragma unroll
        for (int q2 = 0; q2 < 12; ++q2) redC[w][q2] = accC[q2];
        redD[w] = dacc;
    }
    __syncthreads();
    if (t < 12) {
        float s = 0.f, d = 0.f;
        #pragma unroll
        for (int ww = 0; ww < 8; ++ww) { s += redC[ww][t]; d += redD[ww]; }
        d += 2.56e-4f;   // L * 1e-6
        coord_out[bi * 12 + t] = coord[bi * 12 + t] + s / d;
    }
}

// ---------------- node update + LayerNorm ----------------
__global__ __launch_bounds__(128) void k_node(
    const float* __restrict__ h,
    const float* __restrict__ aggI, const float* __restrict__ aggE,
    const float* __restrict__ rel0, const float* __restrict__ rel1,
    const float* __restrict__ nw1, const float* __restrict__ nb1,
    const float* __restrict__ nw2, const float* __restrict__ nb2,
    const float* __restrict__ lnw, const float* __restrict__ lnb,
    float* __restrict__ h_out)
{
    const int r = blockIdx.x, t = threadIdx.x;
    __shared__ float hl[128], aIl[128], aEl[128], a0l[128], a1l[128], hidl[128];
    hl[t]  = h[r * 128 + t];
    aIl[t] = aggI[r * 128 + t];
    aEl[t] = aggE[r * 128 + t];
    __syncthreads();
    float a0 = 0.f, a1 = 0.f;
    #pragma unroll 8
    for (int k = 0; k < 128; ++k) { a0 += aIl[k] * rel0[k * 128 + t]; a1 += aEl[k] * rel1[k * 128 + t]; }
    a0l[t] = a0; a1l[t] = a1;
    __syncthreads();
    float pre = nb1[t];
    #pragma unroll 8
    for (int k = 0; k < 128; ++k) pre += hl[k]  * nw1[k * 128 + t];
    #pragma unroll 8
    for (int k = 0; k < 128; ++k) pre += a0l[k] * nw1[(128 + k) * 128 + t];
    #pragma unroll 8
    for (int k = 0; k < 128; ++k) pre += a1l[k] * nw1[(256 + k) * 128 + t];
    hidl[t] = silu(pre);
    __syncthreads();
    float upd = nb2[t];
    #pragma unroll 8
    for (int k = 0; k < 128; ++k) upd += hidl[k] * nw2[k * 128 + t];
    const float x = hl[t] + upd;
    float s = x, s2 = x * x;
    #pragma unroll
    for (int d = 1; d < 64; d <<= 1) { s += __shfl_xor(s, d, 64); s2 += __shfl_xor(s2, d, 64); }
    __shared__ float rs[2], rs2[2];
    const int wv = t >> 6;
    if ((t & 63) == 0) { rs[wv] = s; rs2[wv] = s2; }
    __syncthreads();
    const float S = rs[0] + rs[1], S2 = rs2[0] + rs2[1];
    const float mu = S * (1.f / 128.f);
    const float var = S2 * (1.f / 128.f) - mu * mu;
    h_out[r * 128 + t] = (x - mu) * rsqrtf(var + 1e-5f) * lnw[t] + lnb[t];
}

// ---------------- edge update via MFMA ----------------
__global__ __launch_bounds__(512) void k_edge_mfma(
    const float* __restrict__ z,
    const float* __restrict__ eA, const float* __restrict__ eB,
    const unsigned short* __restrict__ wE1A,
    const unsigned short* __restrict__ wEW2A,
    const float* __restrict__ eb2,
    float* __restrict__ z_out)
{
    const int bi = blockIdx.x;
    const int b  = bi >> 8;
    const int t  = threadIdx.x;
    const int w  = t >> 6, l = t & 63, g = l >> 4, l15 = l & 15;

    __shared__ __align__(16) unsigned short hidm[256 * 136];  // rows reused fp32 for z_new
    __shared__ float eAl[128];
    __shared__ float eb2l[64];

    if (t < 128)      eAl[t] = eA[bi * 128 + t];
    else if (t < 192) eb2l[t - 128] = eb2[t - 128];
    __syncthreads();

    #pragma unroll 1
    for (int cf = 0; cf < 2; ++cf) {
        asm volatile("" ::: "memory");
        const int j = w * 32 + cf * 16 + l15;
        const float* zrow = z + (size_t)(bi * 256 + j) * 64;

        f32x4 a1[8];
        #pragma unroll
        for (int rf = 0; rf < 8; ++rf) a1[rf] = (f32x4){0.f, 0.f, 0.f, 0.f};
        #pragma unroll
        for (int kk = 0; kk < 2; ++kk) {
            const bf16x8 bf = cvt8(zrow + kk * 32 + g * 8);
            #pragma unroll
            for (int rf = 0; rf < 8; ++rf)
                a1[rf] = __builtin_amdgcn_mfma_f32_16x16x32_bf16(
                    *reinterpret_cast<const bf16x8*>(wE1A + ((kk * 8 + rf) * 64 + l) * 8), bf, a1[rf], 0, 0, 0);
        }

        const float* eBrow = eB + (size_t)(b * 256 + j) * 128;
        #pragma unroll
        for (int rf = 0; rf < 8; ++rf) {
            const int cb = rf * 16 + g * 4;
            const float4 e4 = *reinterpret_cast<const float4*>(eBrow + cb);
            union { __bf16 b4[4]; unsigned long long u; } pk;
            pk.b4[0] = (__bf16)silu(a1[rf][0] + eAl[cb + 0] + e4.x);
            pk.b4[1] = (__bf16)silu(a1[rf][1] + eAl[cb + 1] + e4.y);
            pk.b4[2] = (__bf16)silu(a1[rf][2] + eAl[cb + 2] + e4.z);
            pk.b4[3] = (__bf16)silu(a1[rf][3] + eAl[cb + 3] + e4.w);
            *reinterpret_cast<unsigned long long*>(hidm + (size_t)j * 136 + cb) = pk.u;
        }
        __builtin_amdgcn_wave_barrier();

        f32x4 a2[4];
        #pragma unroll
        for (int rf = 0; rf < 4; ++rf) a2[rf] = (f32x4){0.f, 0.f, 0.f, 0.f};
        #pragma unroll
        for (int kk2 = 0; kk2 < 4; ++kk2) {
            const bf16x8 bf2 = *reinterpret_cast<const bf16x8*>(hidm + (size_t)j * 136 + kk2 * 32 + g * 8);
            #pragma unroll
            for (int rf = 0; rf < 4; ++rf)
                a2[rf] = __builtin_amdgcn_mfma_f32_16x16x32_bf16(
                    *reinterpret_cast<const bf16x8*>(wEW2A + ((kk2 * 4 + rf) * 64 + l) * 8), bf2, a2[rf], 0, 0, 0);
        }
        __builtin_amdgcn_wave_barrier();

        float* zst = reinterpret_cast<float*>(hidm + (size_t)j * 136);
        #pragma unroll
        for (int rf = 0; rf < 4; ++rf) {
            const int p0 = rf * 16 + g * 4;
            float4 v;
            v.x = a2[rf][0] + eb2l[p0 + 0];
            v.y = a2[rf][1] + eb2l[p0 + 1];
            v.z = a2[rf][2] + eb2l[p0 + 2];
            v.w = a2[rf][3] + eb2l[p0 + 3];
            *reinterpret_cast<float4*>(zst + p0) = v;
        }
        __builtin_amdgcn_wave_barrier();
    }

    #pragma unroll
    for (int it = 0; it < 8; ++it) {
        const int chunk = it * 64 + l;
        const int jl = chunk >> 4, oct = chunk & 15;
        const int jr = w * 32 + jl;
        const float4 v = *reinterpret_cast<const float4*>(
            reinterpret_cast<const float*>(hidm + (size_t)jr * 136) + oct * 4);
        *reinterpret_cast<float4*>(z_out + (size_t)(bi * 256 + jr) * 64 + oct * 4) = v;
    }
}

extern "C" void kernel_launch(void* const* d_in, const int* in_sizes, int n_in,
                              void* d_out, int out_size, void* d_ws, size_t ws_size,
                              hipStream_t stream)
{
    (void)in_sizes; (void)n_in; (void)out_size; (void)ws_size;
    const float* coord  = (const float*)d_in[2];
    const float* h      = (const float*)d_in[3];
    const float* z      = (const float*)d_in[4];
    const float* intra  = (const float*)d_in[5];
    const float* inter  = (const float*)d_in[6];
    const float* msg_w1 = (const float*)d_in[7];
    const float* msg_b1 = (const float*)d_in[8];
    const float* msg_w2 = (const float*)d_in[9];
    const float* msg_b2 = (const float*)d_in[10];
    const float* rel_w0 = (const float*)d_in[11];
    const float* rel_w1 = (const float*)d_in[12];
    const float* node_w1= (const float*)d_in[13];
    const float* node_b1= (const float*)d_in[14];
    const float* node_w2= (const float*)d_in[15];
    const float* node_b2= (const float*)d_in[16];
    const float* edge_w1= (const float*)d_in[17];
    const float* edge_b1= (const float*)d_in[18];
    const float* edge_w2= (const float*)d_in[19];
    const float* edge_b2= (const float*)d_in[20];
    const float* c0w1   = (const float*)d_in[21];
    const float* c0w2   = (const float*)d_in[23];
    const float* c1w1   = (const float*)d_in[24];
    const float* c1w2   = (const float*)d_in[26];
    const float* lnw    = (const float*)d_in[27];
    const float* lnb    = (const float*)d_in[28];

    float* out       = (float*)d_out;
    float* coord_out = out;                       // [N,L,C,3]   12288
    float* h_out     = out + 12288;               // [N,L,D]     131072
    float* z_out     = out + 12288 + 131072;      // [N,L,L,P]   16777216

    float* ws      = (float*)d_ws;
    float* partial = ws;                          // 16384
    float* rnorm   = ws + 16384;
    float* hA      = ws + 16448;                  // 131072
    float* hB      = hA + 131072;                 // (unused, layout kept)
    float* aggI    = hB + 131072;
    float* aggE    = aggI + 131072;
    float* eA      = aggE + 131072;
    float* eB      = eA + 131072;
    unsigned short* wsA    = (unsigned short*)(eB + 131072);  // 32768 us (coord A-frags)
    unsigned short* wsMsgA = wsA + 32768;                     // 28672 us (msg GEMM1 A-frags)
    unsigned short* wsW2A  = wsMsgA + 28672;                  // 16384 us (msg W2 A-frags)
    unsigned short* wsE1A  = wsW2A + 16384;                   //  8192 us (edge GEMM1 A-frags)
    unsigned short* wsEW2A = wsE1A + 8192;                    //  8192 us (edge W2 A-frags)
    // m (bf16) lives in the z_new output region (67 MB exact fit, consumed before k_edge).
    unsigned short* m_bf = (unsigned short*)z_out;

    k_norm_partial<<<1024, 256, 0, stream>>>(coord, partial);
    k_norm_finish<<<1, 256, 0, stream>>>(partial, rnorm);
    k_pack_coord_w<<<128, 256, 0, stream>>>(c0w1, c1w1, wsA);
    k_pack_msg_w<<<176, 256, 0, stream>>>(msg_w1, msg_w2, wsMsgA, wsW2A);
    k_pack_edge_w<<<64, 256, 0, stream>>>(edge_w1, edge_w2, wsE1A, wsEW2A);
    k_pre_hA<<<1024, 128, 0, stream>>>(h, msg_w1, msg_b1, hA);
    k_msg_mfma<<<1024, 512, 0, stream>>>(coord, h, z, hA, wsMsgA, wsW2A,
                                         msg_b2, rnorm, m_bf);
    k_agg<<<1024, 256, 0, stream>>>(m_bf, intra, inter, aggI, aggE);
    k_coord_mfma<<<1024, 512, 0, stream>>>(coord, m_bf, intra, inter, wsA,
                                           c0w2, c1w2, coord_out);
    k_node<<<1024, 128, 0, stream>>>(h, aggI, aggE, rel_w0, rel_w1,
                                     node_w1, node_b1, node_w2, node_b2, lnw, lnb, h_out);
    k_pre_msg<<<1024, 256, 0, stream>>>(h_out, edge_w1, edge_b1, eA, eB);
    k_edge_mfma<<<1024, 512, 0, stream>>>(z, eA, eB, wsE1A, wsEW2A, edge_b2, z_out);
}

// Round 9
// 271.836 us; speedup vs baseline: 2.1011x; 1.0363x over previous
//
#include <hip/hip_runtime.h>

// SABlock: EGNN-style block. N=4, L=256, D=128, P=64, C=4.
//   k_prep      : fat kernel — norm_partial | pack coord/msg/edge frags | pre_hA | h,z->bf16
//   k_norm_finish : rnorm[16]
//   k_msg_mfma  : GEMM1 (K=224) -> silu -> GEMM2 -> m bf16  (ZBF: bf16 h/z direct loads)
//   k_agg       : aggI/aggE from m_bf (memory-bound)
//   k_coord_mfma: coord MLPs on MFMA + coord update epilogue
//   k_node      : node MLP + LayerNorm
//   k_pre_msg   : eA/eB for edge path (uses h_new)
//   k_edge_mfma : GEMM1 (K=64, z) -> silu(+eA+eB) -> GEMM2 (K=128) -> z_new fp32

#define DEV static __device__ __forceinline__

DEV float silu(float x) { return x / (1.0f + __expf(-x)); }

DEV float bf2f(unsigned short u) {
    unsigned int v = ((unsigned int)u) << 16;
    float f;
    __builtin_memcpy(&f, &v, 4);
    return f;
}
DEV unsigned short f2bf(float f) {
    unsigned int x;
    __builtin_memcpy(&x, &f, 4);
    x += 0x7fffu + ((x >> 16) & 1u);
    return (unsigned short)(x >> 16);
}

struct __align__(8) US4 { unsigned short x, y, z, w; };

typedef __bf16 bf16x8 __attribute__((ext_vector_type(8)));
typedef float  f32x4  __attribute__((ext_vector_type(4)));

DEV bf16x8 cvt8(const float* p) {
    const float4 a = *reinterpret_cast<const float4*>(p);
    const float4 c = *reinterpret_cast<const float4*>(p + 4);
    bf16x8 r;
    r[0] = (__bf16)a.x; r[1] = (__bf16)a.y; r[2] = (__bf16)a.z; r[3] = (__bf16)a.w;
    r[4] = (__bf16)c.x; r[5] = (__bf16)c.y; r[6] = (__bf16)c.z; r[7] = (__bf16)c.w;
    return r;
}

// ---------------- fat prep kernel ----------------
// blk ranges: [0,1024) norm_partial | [1024,1152) pack coord | [1152,1328) pack msg
//             [1328,1392) pack edge | [1392,1904) pre_hA     | [1904,1968) h->bf16
//             [1968,10160) z->bf16 (only when do_cvt)
__global__ __launch_bounds__(256) void k_prep(
    const float* __restrict__ coord, const float* __restrict__ h,
    const float* __restrict__ z,
    const float* __restrict__ msg_w1, const float* __restrict__ msg_b1,
    const float* __restrict__ msg_w2,
    const float* __restrict__ edge_w1, const float* __restrict__ edge_w2,
    const float* __restrict__ c0w1, const float* __restrict__ c1w1,
    float* __restrict__ partial, float* __restrict__ hA,
    unsigned short* __restrict__ wsA, unsigned short* __restrict__ wsMsgA,
    unsigned short* __restrict__ wsW2A,
    unsigned short* __restrict__ wE1A, unsigned short* __restrict__ wEW2A,
    unsigned short* __restrict__ h_bf, unsigned short* __restrict__ z_bf)
{
    const int blk = blockIdx.x;
    const int t = threadIdx.x;
    __shared__ float red[4][16];
    __shared__ float hl2[2][128];

    if (blk < 1024) {
        // norm_partial
        const int r = blk * 256 + t;
        const int b = r >> 16, rem = r & 0xFFFF, i = rem >> 8, j = rem & 255;
        const float* ci = coord + (b * 256 + i) * 12;
        const float* cj = coord + (b * 256 + j) * 12;
        float cd[4][3];
        #pragma unroll
        for (int c = 0; c < 4; ++c)
            #pragma unroll
            for (int x = 0; x < 3; ++x)
                cd[c][x] = ci[c * 3 + x] - cj[c * 3 + x];
        float sq[16];
        #pragma unroll
        for (int m = 0; m < 4; ++m)
            #pragma unroll
            for (int p = 0; p < 4; ++p) {
                float v = cd[m][0] * cd[p][0] + cd[m][1] * cd[p][1] + cd[m][2] * cd[p][2];
                sq[m * 4 + p] = v * v;
            }
        #pragma unroll
        for (int s = 1; s < 64; s <<= 1)
            #pragma unroll
            for (int qq = 0; qq < 16; ++qq)
                sq[qq] += __shfl_xor(sq[qq], s, 64);
        const int wave = t >> 6, lane = t & 63;
        if (lane == 0)
            #pragma unroll
            for (int qq = 0; qq < 16; ++qq) red[wave][qq] = sq[qq];
        __syncthreads();
        if (t < 16)
            partial[blk * 16 + t] = red[0][t] + red[1][t] + red[2][t] + red[3][t];
    } else if (blk < 1152) {
        // pack coord weights
        const int o = (blk - 1024) * 256 + t;         // < 32768
        const int p  = o >> 14;
        const int r  = o & 16383;
        const int jj = r & 7, l = (r >> 3) & 63, rf = (r >> 9) & 7, kk = r >> 12;
        const int k = kk * 32 + ((l >> 4) << 3) + jj;
        const int c = (rf << 4) + (l & 15);
        const float* W = p ? c1w1 : c0w1;
        wsA[o] = f2bf(W[k * 128 + c]);
    } else if (blk < 1328) {
        // pack msg weights
        const int o = (blk - 1152) * 256 + t;         // < 45056
        if (o < 16384) {
            const int jj = o & 7, l = (o >> 3) & 63, rf = (o >> 9) & 7, kk = o >> 12;
            const int k = kk * 32 + ((l >> 4) << 3) + jj;
            const int c = (rf << 4) + (l & 15);
            wsMsgA[o] = f2bf(msg_w1[(128 + k) * 128 + c]);
        } else if (o < 20480) {
            const int o2 = o - 16384;
            const int jj = o2 & 7, l = (o2 >> 3) & 63, rf = (o2 >> 9) & 7;
            const int k = ((l >> 4) << 3) + jj;
            const int c = (rf << 4) + (l & 15);
            wsMsgA[o] = (k < 16) ? f2bf(msg_w1[(256 + k) * 128 + c]) : (unsigned short)0;
        } else if (o < 28672) {
            const int o3 = o - 20480;
            const int jj = o3 & 7, l = (o3 >> 3) & 63, rf = (o3 >> 9) & 7, kk = o3 >> 12;
            const int k = kk * 32 + ((l >> 4) << 3) + jj;
            const int c = (rf << 4) + (l & 15);
            wsMsgA[o] = f2bf(msg_w1[(272 + k) * 128 + c]);
        } else {
            const int o2 = o - 28672;                 // < 16384
            const int jj = o2 & 7, l = (o2 >> 3) & 63, rf = (o2 >> 9) & 7, kk2 = o2 >> 12;
            const int c  = kk2 * 32 + ((l >> 4) << 3) + jj;
            const int c2 = (rf << 4) + (l & 15);
            wsW2A[o2] = f2bf(msg_w2[c * 128 + c2]);
        }
    } else if (blk < 1392) {
        // pack edge weights
        const int o = (blk - 1328) * 256 + t;         // < 16384
        if (o < 8192) {
            const int jj = o & 7, l = (o >> 3) & 63, rf = (o >> 9) & 7, kk = o >> 12;
            const int k = kk * 32 + ((l >> 4) << 3) + jj;
            const int c = (rf << 4) + (l & 15);
            wE1A[o] = f2bf(edge_w1[(256 + k) * 128 + c]);
        } else {
            const int o2 = o - 8192;
            const int jj = o2 & 7, l = (o2 >> 3) & 63, rf = (o2 >> 9) & 3, kk2 = o2 >> 11;
            const int k = kk2 * 32 + ((l >> 4) << 3) + jj;
            const int p = (rf << 4) + (l & 15);
            wEW2A[o2] = f2bf(edge_w2[k * 64 + p]);
        }
    } else if (blk < 1904) {
        // pre_hA: 2 rows per block
        const int rr = (blk - 1392) * 2 + (t >> 7);
        const int c = t & 127;
        hl2[t >> 7][c] = h[rr * 128 + c];
        __syncthreads();
        float acc = msg_b1[c];
        #pragma unroll 8
        for (int k = 0; k < 128; ++k) acc += hl2[t >> 7][k] * msg_w1[k * 128 + c];
        hA[rr * 128 + c] = acc;
    } else if (blk < 1968) {
        // h -> bf16
        const int i0 = (blk - 1904) * 2048 + t * 8;   // < 131072
        const bf16x8 v = cvt8(h + i0);
        *reinterpret_cast<bf16x8*>(h_bf + i0) = v;
    } else {
        // z -> bf16
        const size_t i0 = (size_t)(blk - 1968) * 2048 + t * 8;  // < 16777216
        const bf16x8 v = cvt8(z + i0);
        *reinterpret_cast<bf16x8*>(z_bf + i0) = v;
    }
}

__global__ __launch_bounds__(256) void k_norm_finish(const float* __restrict__ partial,
                                                     float* __restrict__ rnorm)
{
    const int t = threadIdx.x;
    const int cc = t & 15, g = t >> 4;
    float s = 0.f;
    for (int k = 0; k < 64; ++k) s += partial[(g * 64 + k) * 16 + cc];
    __shared__ float red[16][17];
    red[g][cc] = s;
    __syncthreads();
    if (t < 16) {
        float tot = 0.f;
        #pragma unroll
        for (int gg = 0; gg < 16; ++gg) tot += red[gg][t];
        rnorm[t] = 1.0f / fmaxf(sqrtf(tot), 1e-12f);
    }
}

// ---------------- row-precompute for edge path ----------------
__global__ __launch_bounds__(256) void k_pre_msg(const float* __restrict__ h,
                                                 const float* __restrict__ w1,
                                                 const float* __restrict__ b1,
                                                 float* __restrict__ hA,
                                                 float* __restrict__ hB)
{
    const int r = blockIdx.x;
    const int t = threadIdx.x;
    const int half = t >> 7, c = t & 127;
    __shared__ float hl[128];
    if (t < 128) hl[t] = h[r * 128 + t];
    __syncthreads();
    const float* W = w1 + half * 128 * 128;
    float acc = half ? 0.f : b1[c];
    #pragma unroll 8
    for (int k = 0; k < 128; ++k) acc += hl[k] * W[k * 128 + c];
    (half ? hB : hA)[r * 128 + c] = acc;
}

// ---------------- message MLP via MFMA (v5: bf16 direct loads when ZBF) ----------------
template<int ZBF>
__global__ __launch_bounds__(512) void k_msg_mfma(
    const float* __restrict__ coord, const float* __restrict__ h,
    const float* __restrict__ z,
    const unsigned short* __restrict__ h_bf, const unsigned short* __restrict__ z_bf,
    const float* __restrict__ hA,
    const unsigned short* __restrict__ wsMsgA,
    const unsigned short* __restrict__ wsW2A,
    const float* __restrict__ msg_b2, const float* __restrict__ rnorm,
    unsigned short* __restrict__ m_out)
{
    const int bi = blockIdx.x;
    const int b  = bi >> 8;
    const int t  = threadIdx.x;
    const int w  = t >> 6, l = t & 63, g = l >> 4, l15 = l & 15;

    __shared__ __align__(16) unsigned short A1[20480];        // 40960 B: hj + rad frags
    __shared__ __align__(16) unsigned short hidm[128 * 136];  // 34816 B: per-phase rows
    __shared__ float hAl[128], b2l[128];
    __shared__ float cil[12];
    __shared__ float rnl[16];

    {
        const float4* src = reinterpret_cast<const float4*>(wsMsgA);
        float4* dst = reinterpret_cast<float4*>(A1);
        #pragma unroll
        for (int it = 0; it < 5; ++it) dst[it * 512 + t] = src[it * 512 + t];
    }
    if (t < 12) cil[t] = coord[bi * 12 + t];
    if (t < 16) rnl[t] = rnorm[t];
    if (t < 128)      hAl[t] = hA[bi * 128 + t];
    else if (t < 256) b2l[t - 128] = msg_b2[t - 128];
    __syncthreads();

    const int row = w * 16 + l15;
    const size_t rb = (size_t)row * 136;

    #pragma unroll 1
    for (int cf = 0; cf < 2; ++cf) {
        const int j = w * 32 + cf * 16 + l15;

        // rad B-frag inline
        bf16x8 radB;
        {
            const float* cj = coord + (size_t)(b * 256 + j) * 12;
            float cd[12];
            #pragma unroll
            for (int x = 0; x < 12; ++x) cd[x] = cil[x] - cj[x];
            #pragma unroll
            for (int e = 0; e < 8; ++e) {
                const int k = g * 8 + e;
                float v = 0.f;
                if (k < 16) {
                    const int mm = k >> 2, pp = k & 3;
                    v = (cd[mm*3+0]*cd[pp*3+0] + cd[mm*3+1]*cd[pp*3+1] + cd[mm*3+2]*cd[pp*3+2]) * rnl[k];
                }
                radB[e] = (__bf16)v;
            }
        }

        f32x4 a1[8];
        #pragma unroll
        for (int rf = 0; rf < 8; ++rf) a1[rf] = (f32x4){0.f, 0.f, 0.f, 0.f};

        #pragma unroll
        for (int kk = 0; kk < 4; ++kk) {
            bf16x8 bf;
            if constexpr (ZBF) bf = *reinterpret_cast<const bf16x8*>(h_bf + (size_t)(b * 256 + j) * 128 + kk * 32 + g * 8);
            else               bf = cvt8(h + (size_t)(b * 256 + j) * 128 + kk * 32 + g * 8);
            #pragma unroll
            for (int rf = 0; rf < 8; ++rf)
                a1[rf] = __builtin_amdgcn_mfma_f32_16x16x32_bf16(
                    *reinterpret_cast<const bf16x8*>(A1 + ((kk * 8 + rf) * 64 + l) * 8), bf, a1[rf], 0, 0, 0);
        }
        #pragma unroll
        for (int kk = 0; kk < 2; ++kk) {
            bf16x8 bf;
            if constexpr (ZBF) bf = *reinterpret_cast<const bf16x8*>(z_bf + (size_t)(bi * 256 + j) * 64 + kk * 32 + g * 8);
            else               bf = cvt8(z + (size_t)(bi * 256 + j) * 64 + kk * 32 + g * 8);
            #pragma unroll
            for (int rf = 0; rf < 8; ++rf)
                a1[rf] = __builtin_amdgcn_mfma_f32_16x16x32_bf16(
                    *reinterpret_cast<const bf16x8*>(wsMsgA + 20480 + ((kk * 8 + rf) * 64 + l) * 8), bf, a1[rf], 0, 0, 0);
        }
        #pragma unroll
        for (int rf = 0; rf < 8; ++rf)
            a1[rf] = __builtin_amdgcn_mfma_f32_16x16x32_bf16(
                *reinterpret_cast<const bf16x8*>(A1 + 16384 + (rf * 64 + l) * 8), radB, a1[rf], 0, 0, 0);

        // hidden = silu(acc + hA[c]) -> bf16 into this lane's hidm row
        #pragma unroll
        for (int rf = 0; rf < 8; ++rf) {
            const int cb = rf * 16 + g * 4;
            union { __bf16 b4[4]; unsigned long long u; } pk;
            #pragma unroll
            for (int r = 0; r < 4; ++r) pk.b4[r] = (__bf16)silu(a1[rf][r] + hAl[cb + r]);
            *reinterpret_cast<unsigned long long*>(hidm + rb + cb) = pk.u;
        }
        __builtin_amdgcn_wave_barrier();

        // GEMM2: m^T = W2^T x hidden^T
        f32x4 a2[8];
        #pragma unroll
        for (int rf = 0; rf < 8; ++rf) a2[rf] = (f32x4){0.f, 0.f, 0.f, 0.f};
        #pragma unroll
        for (int kk2 = 0; kk2 < 4; ++kk2) {
            const bf16x8 bf2 = *reinterpret_cast<const bf16x8*>(hidm + rb + kk2 * 32 + g * 8);
            #pragma unroll
            for (int rf = 0; rf < 8; ++rf)
                a2[rf] = __builtin_amdgcn_mfma_f32_16x16x32_bf16(
                    *reinterpret_cast<const bf16x8*>(wsW2A + ((kk2 * 8 + rf) * 64 + l) * 8), bf2, a2[rf], 0, 0, 0);
        }
        __builtin_amdgcn_wave_barrier();

        // epilogue: +b2, pack m (bf16) over the hidm row
        #pragma unroll
        for (int rf = 0; rf < 8; ++rf) {
            const int cb = rf * 16 + g * 4;
            union { __bf16 b4[4]; unsigned long long u; } pk;
            #pragma unroll
            for (int r = 0; r < 4; ++r) pk.b4[r] = (__bf16)(a2[rf][r] + b2l[cb + r]);
            *reinterpret_cast<unsigned long long*>(hidm + rb + cb) = pk.u;
        }
        __builtin_amdgcn_wave_barrier();

        // flush wave's 16 rows -> m_out
        #pragma unroll
        for (int it = 0; it < 4; ++it) {
            const int c2 = it * 64 + l;
            const int rl = c2 >> 4, oct = c2 & 15;
            const uint4 v = *reinterpret_cast<const uint4*>(hidm + (size_t)(w * 16 + rl) * 136 + oct * 8);
            *reinterpret_cast<uint4*>(m_out + ((size_t)(bi * 256 + w * 32 + cf * 16 + rl)) * 128 + oct * 8) = v;
        }
        __builtin_amdgcn_wave_barrier();
    }
}

// ---------------- masked aggregates from m (memory-bound) ----------------
__global__ __launch_bounds__(256) void k_agg(
    const unsigned short* __restrict__ m_in,
    const float* __restrict__ intra, const float* __restrict__ inter,
    float* __restrict__ aggI, float* __restrict__ aggE)
{
    const int bi = blockIdx.x;
    const int t  = threadIdx.x;
    const int oct = t & 15;
    const int jg  = t >> 4;
    __shared__ float iml[256], eml[256];
    __shared__ float red[2][16][128];
    iml[t] = intra[bi * 256 + t];
    eml[t] = inter[bi * 256 + t];
    __syncthreads();
    float accI[8], accE[8];
    #pragma unroll
    for (int e = 0; e < 8; ++e) { accI[e] = 0.f; accE[e] = 0.f; }
    #pragma unroll 4
    for (int jj = 0; jj < 16; ++jj) {
        const int j = jj * 16 + jg;
        union { uint4 u4; unsigned short us[8]; } v;
        v.u4 = *reinterpret_cast<const uint4*>(m_in + ((size_t)(bi * 256 + j)) * 128 + oct * 8);
        const float wI = iml[j], wE = eml[j];
        #pragma unroll
        for (int e = 0; e < 8; ++e) {
            const float mv = bf2f(v.us[e]);
            accI[e] += mv * wI;
            accE[e] += mv * wE;
        }
    }
    #pragma unroll
    for (int e = 0; e < 8; ++e) {
        red[0][jg][oct * 8 + e] = accI[e];
        red[1][jg][oct * 8 + e] = accE[e];
    }
    __syncthreads();
    if (t < 128) {
        float sI = 0.f, sE = 0.f;
        #pragma unroll
        for (int q = 0; q < 16; ++q) { sI += red[0][q][t]; sE += red[1][q][t]; }
        aggI[bi * 128 + t] = sI;
        aggE[bi * 128 + t] = sE;
    }
}

// ---------------- coord update via MFMA ----------------
__global__ __launch_bounds__(512) void k_coord_mfma(
    const float* __restrict__ coord,
    const unsigned short* __restrict__ m_in,
    const float* __restrict__ intra, const float* __restrict__ inter,
    const unsigned short* __restrict__ wsA,
    const float* __restrict__ c0w2, const float* __restrict__ c1w2,
    float* __restrict__ coord_out)
{
    const int bi = blockIdx.x;
    const int b  = bi >> 8;
    const int t  = threadIdx.x;
    const int w  = t >> 6;
    const int l  = t & 63;
    const int g  = l >> 4;
    const int l15 = l & 15;

    __shared__ __align__(16) unsigned short Apk[2 * 16384];
    __shared__ __align__(16) float W2l[2 * 128 * 4];
    __shared__ float iml[256], eml[256];
    __shared__ float cil[12];
    __shared__ float redC[8][12];
    __shared__ float redD[8];

    {
        const float4* srcA = reinterpret_cast<const float4*>(wsA);
        float4* dstA = reinterpret_cast<float4*>(Apk);
        for (int idx = t; idx < 4096; idx += 512) dstA[idx] = srcA[idx];
        if (t < 512) { W2l[t] = c0w2[t]; W2l[512 + t] = c1w2[t]; }
        if (t < 256) { iml[t] = intra[bi * 256 + t]; eml[t] = inter[bi * 256 + t]; }
        if (t < 12)  cil[t] = coord[bi * 12 + t];
    }
    __syncthreads();

    f32x4 acc[2][2][8];
    #pragma unroll
    for (int p = 0; p < 2; ++p)
        #pragma unroll
        for (int cf = 0; cf < 2; ++cf)
            #pragma unroll
            for (int rf = 0; rf < 8; ++rf)
                acc[p][cf][rf] = (f32x4){0.f, 0.f, 0.f, 0.f};

    #pragma unroll
    for (int kk = 0; kk < 4; ++kk) {
        bf16x8 bfr[2];
        #pragma unroll
        for (int cf = 0; cf < 2; ++cf) {
            const size_t mo = ((size_t)(bi * 256 + w * 32 + cf * 16 + l15)) * 128 + kk * 32 + g * 8;
            bfr[cf] = *reinterpret_cast<const bf16x8*>(m_in + mo);
        }
        #pragma unroll
        for (int rf = 0; rf < 8; ++rf) {
            const bf16x8 a0 = *reinterpret_cast<const bf16x8*>(Apk + ((kk * 8 + rf) * 64 + l) * 8);
            const bf16x8 a1 = *reinterpret_cast<const bf16x8*>(Apk + 16384 + ((kk * 8 + rf) * 64 + l) * 8);
            acc[0][0][rf] = __builtin_amdgcn_mfma_f32_16x16x32_bf16(a0, bfr[0], acc[0][0][rf], 0, 0, 0);
            acc[0][1][rf] = __builtin_amdgcn_mfma_f32_16x16x32_bf16(a0, bfr[1], acc[0][1][rf], 0, 0, 0);
            acc[1][0][rf] = __builtin_amdgcn_mfma_f32_16x16x32_bf16(a1, bfr[0], acc[1][0][rf], 0, 0, 0);
            acc[1][1][rf] = __builtin_amdgcn_mfma_f32_16x16x32_bf16(a1, bfr[1], acc[1][1][rf], 0, 0, 0);
        }
    }

    float wf[2][2][4];
    #pragma unroll
    for (int p = 0; p < 2; ++p)
        #pragma unroll
        for (int cf = 0; cf < 2; ++cf)
            #pragma unroll
            for (int pc = 0; pc < 4; ++pc) wf[p][cf][pc] = 0.f;

    #pragma unroll
    for (int p = 0; p < 2; ++p)
        #pragma unroll
        for (int rf = 0; rf < 8; ++rf)
            #pragma unroll
            for (int r = 0; r < 4; ++r) {
                const int c = rf * 16 + g * 4 + r;
                const float4 w2 = *reinterpret_cast<const float4*>(&W2l[(p * 128 + c) * 4]);
                #pragma unroll
                for (int cf = 0; cf < 2; ++cf) {
                    const float hid = silu(acc[p][cf][rf][r]);
                    wf[p][cf][0] += hid * w2.x;
                    wf[p][cf][1] += hid * w2.y;
                    wf[p][cf][2] += hid * w2.z;
                    wf[p][cf][3] += hid * w2.w;
                }
            }

    float accC[12];
    #pragma unroll
    for (int q2 = 0; q2 < 12; ++q2) accC[q2] = 0.f;
    float dacc = 0.f;

    #pragma unroll
    for (int cf = 0; cf < 2; ++cf) {
        float w0c[4], w1c[4];
        #pragma unroll
        for (int pc = 0; pc < 4; ++pc) { w0c[pc] = wf[0][cf][pc]; w1c[pc] = wf[1][cf][pc]; }
        #pragma unroll
        for (int pc = 0; pc < 4; ++pc) {
            w0c[pc] += __shfl_xor(w0c[pc], 16, 64); w0c[pc] += __shfl_xor(w0c[pc], 32, 64);
            w1c[pc] += __shfl_xor(w1c[pc], 16, 64); w1c[pc] += __shfl_xor(w1c[pc], 32, 64);
        }
        const int j = w * 32 + cf * 16 + l15;
        const float im = iml[j], em = eml[j];
        float wt[4];
        #pragma unroll
        for (int pc = 0; pc < 4; ++pc) wt[pc] = w0c[pc] * im + w1c[pc] * em;
        const float* cjp = coord + (size_t)(b * 256 + j) * 12;
        const float4 cj0 = *reinterpret_cast<const float4*>(cjp);
        const float4 cj1 = *reinterpret_cast<const float4*>(cjp + 4);
        const float4 cj2 = *reinterpret_cast<const float4*>(cjp + 8);
        accC[0]  += (cil[0]  - cj0.x) * wt[0];
        accC[1]  += (cil[1]  - cj0.y) * wt[0];
        accC[2]  += (cil[2]  - cj0.z) * wt[0];
        accC[3]  += (cil[3]  - cj0.w) * wt[1];
        accC[4]  += (cil[4]  - cj1.x) * wt[1];
        accC[5]  += (cil[5]  - cj1.y) * wt[1];
        accC[6]  += (cil[6]  - cj1.z) * wt[2];
        accC[7]  += (cil[7]  - cj1.w) * wt[2];
        accC[8]  += (cil[8]  - cj2.x) * wt[2];
        accC[9]  += (cil[9]  - cj2.y) * wt[3];
        accC[10] += (cil[10] - cj2.z) * wt[3];
        accC[11] += (cil[11] - cj2.w) * wt[3];
        dacc += im + em;
    }
    #pragma unroll
    for (int s = 1; s < 16; s <<= 1) {
        #pragma unroll
        for (int q2 = 0; q2 < 12; ++q2) accC[q2] += __shfl_xor(accC[q2], s, 64);
        dacc += __shfl_xor(dacc, s, 64);
    }
    if (l == 0) {
        #pragma unroll
        for (int q2 = 0; q2 < 12; ++q2) redC[w][q2] = accC[q2];
        redD[w] = dacc;
    }
    __syncthreads();
    if (t < 12) {
        float s = 0.f, d = 0.f;
        #pragma unroll
        for (int ww = 0; ww < 8; ++ww) { s += redC[ww][t]; d += redD[ww]; }
        d += 2.56e-4f;   // L * 1e-6
        coord_out[bi * 12 + t] = coord[bi * 12 + t] + s / d;
    }
}

// ---------------- node update + LayerNorm ----------------
__global__ __launch_bounds__(128) void k_node(
    const float* __restrict__ h,
    const float* __restrict__ aggI, const float* __restrict__ aggE,
    const float* __restrict__ rel0, const float* __restrict__ rel1,
    const float* __restrict__ nw1, const float* __restrict__ nb1,
    const float* __restrict__ nw2, const float* __restrict__ nb2,
    const float* __restrict__ lnw, const float* __restrict__ lnb,
    float* __restrict__ h_out)
{
    const int r = blockIdx.x, t = threadIdx.x;
    __shared__ float hl[128], aIl[128], aEl[128], a0l[128], a1l[128], hidl[128];
    hl[t]  = h[r * 128 + t];
    aIl[t] = aggI[r * 128 + t];
    aEl[t] = aggE[r * 128 + t];
    __syncthreads();
    float a0 = 0.f, a1 = 0.f;
    #pragma unroll 8
    for (int k = 0; k < 128; ++k) { a0 += aIl[k] * rel0[k * 128 + t]; a1 += aEl[k] * rel1[k * 128 + t]; }
    a0l[t] = a0; a1l[t] = a1;
    __syncthreads();
    float pre = nb1[t];
    #pragma unroll 8
    for (int k = 0; k < 128; ++k) pre += hl[k]  * nw1[k * 128 + t];
    #pragma unroll 8
    for (int k = 0; k < 128; ++k) pre += a0l[k] * nw1[(128 + k) * 128 + t];
    #pragma unroll 8
    for (int k = 0; k < 128; ++k) pre += a1l[k] * nw1[(256 + k) * 128 + t];
    hidl[t] = silu(pre);
    __syncthreads();
    float upd = nb2[t];
    #pragma unroll 8
    for (int k = 0; k < 128; ++k) upd += hidl[k] * nw2[k * 128 + t];
    const float x = hl[t] + upd;
    float s = x, s2 = x * x;
    #pragma unroll
    for (int d = 1; d < 64; d <<= 1) { s += __shfl_xor(s, d, 64); s2 += __shfl_xor(s2, d, 64); }
    __shared__ float rs[2], rs2[2];
    const int wv = t >> 6;
    if ((t & 63) == 0) { rs[wv] = s; rs2[wv] = s2; }
    __syncthreads();
    const float S = rs[0] + rs[1], S2 = rs2[0] + rs2[1];
    const float mu = S * (1.f / 128.f);
    const float var = S2 * (1.f / 128.f) - mu * mu;
    h_out[r * 128 + t] = (x - mu) * rsqrtf(var + 1e-5f) * lnw[t] + lnb[t];
}

// ---------------- edge update via MFMA ----------------
template<int ZBF>
__global__ __launch_bounds__(512) void k_edge_mfma(
    const float* __restrict__ z, const unsigned short* __restrict__ z_bf,
    const float* __restrict__ eA, const float* __restrict__ eB,
    const unsigned short* __restrict__ wE1A,
    const unsigned short* __restrict__ wEW2A,
    const float* __restrict__ eb2,
    float* __restrict__ z_out)
{
    const int bi = blockIdx.x;
    const int b  = bi >> 8;
    const int t  = threadIdx.x;
    const int w  = t >> 6, l = t & 63, g = l >> 4, l15 = l & 15;

    __shared__ __align__(16) unsigned short hidm[256 * 136];  // rows reused fp32 for z_new
    __shared__ float eAl[128];
    __shared__ float eb2l[64];

    if (t < 128)      eAl[t] = eA[bi * 128 + t];
    else if (t < 192) eb2l[t - 128] = eb2[t - 128];
    __syncthreads();

    #pragma unroll 1
    for (int cf = 0; cf < 2; ++cf) {
        asm volatile("" ::: "memory");
        const int j = w * 32 + cf * 16 + l15;

        f32x4 a1[8];
        #pragma unroll
        for (int rf = 0; rf < 8; ++rf) a1[rf] = (f32x4){0.f, 0.f, 0.f, 0.f};
        #pragma unroll
        for (int kk = 0; kk < 2; ++kk) {
            bf16x8 bf;
            if constexpr (ZBF) bf = *reinterpret_cast<const bf16x8*>(z_bf + (size_t)(bi * 256 + j) * 64 + kk * 32 + g * 8);
            else               bf = cvt8(z + (size_t)(bi * 256 + j) * 64 + kk * 32 + g * 8);
            #pragma unroll
            for (int rf = 0; rf < 8; ++rf)
                a1[rf] = __builtin_amdgcn_mfma_f32_16x16x32_bf16(
                    *reinterpret_cast<const bf16x8*>(wE1A + ((kk * 8 + rf) * 64 + l) * 8), bf, a1[rf], 0, 0, 0);
        }

        const float* eBrow = eB + (size_t)(b * 256 + j) * 128;
        #pragma unroll
        for (int rf = 0; rf < 8; ++rf) {
            const int cb = rf * 16 + g * 4;
            const float4 e4 = *reinterpret_cast<const float4*>(eBrow + cb);
            union { __bf16 b4[4]; unsigned long long u; } pk;
            pk.b4[0] = (__bf16)silu(a1[rf][0] + eAl[cb + 0] + e4.x);
            pk.b4[1] = (__bf16)silu(a1[rf][1] + eAl[cb + 1] + e4.y);
            pk.b4[2] = (__bf16)silu(a1[rf][2] + eAl[cb + 2] + e4.z);
            pk.b4[3] = (__bf16)silu(a1[rf][3] + eAl[cb + 3] + e4.w);
            *reinterpret_cast<unsigned long long*>(hidm + (size_t)j * 136 + cb) = pk.u;
        }
        __builtin_amdgcn_wave_barrier();

        f32x4 a2[4];
        #pragma unroll
        for (int rf = 0; rf < 4; ++rf) a2[rf] = (f32x4){0.f, 0.f, 0.f, 0.f};
        #pragma unroll
        for (int kk2 = 0; kk2 < 4; ++kk2) {
            const bf16x8 bf2 = *reinterpret_cast<const bf16x8*>(hidm + (size_t)j * 136 + kk2 * 32 + g * 8);
            #pragma unroll
            for (int rf = 0; rf < 4; ++rf)
                a2[rf] = __builtin_amdgcn_mfma_f32_16x16x32_bf16(
                    *reinterpret_cast<const bf16x8*>(wEW2A + ((kk2 * 4 + rf) * 64 + l) * 8), bf2, a2[rf], 0, 0, 0);
        }
        __builtin_amdgcn_wave_barrier();

        float* zst = reinterpret_cast<float*>(hidm + (size_t)j * 136);
        #pragma unroll
        for (int rf = 0; rf < 4; ++rf) {
            const int p0 = rf * 16 + g * 4;
            float4 v;
            v.x = a2[rf][0] + eb2l[p0 + 0];
            v.y = a2[rf][1] + eb2l[p0 + 1];
            v.z = a2[rf][2] + eb2l[p0 + 2];
            v.w = a2[rf][3] + eb2l[p0 + 3];
            *reinterpret_cast<float4*>(zst + p0) = v;
        }
        __builtin_amdgcn_wave_barrier();
    }

    #pragma unroll
    for (int it = 0; it < 8; ++it) {
        const int chunk = it * 64 + l;
        const int jl = chunk >> 4, oct = chunk & 15;
        const int jr = w * 32 + jl;
        const float4 v = *reinterpret_cast<const float4*>(
            reinterpret_cast<const float*>(hidm + (size_t)jr * 136) + oct * 4);
        *reinterpret_cast<float4*>(z_out + (size_t)(bi * 256 + jr) * 64 + oct * 4) = v;
    }
}

extern "C" void kernel_launch(void* const* d_in, const int* in_sizes, int n_in,
                              void* d_out, int out_size, void* d_ws, size_t ws_size,
                              hipStream_t stream)
{
    (void)in_sizes; (void)n_in; (void)out_size;
    const float* coord  = (const float*)d_in[2];
    const float* h      = (const float*)d_in[3];
    const float* z      = (const float*)d_in[4];
    const float* intra  = (const float*)d_in[5];
    const float* inter  = (const float*)d_in[6];
    const float* msg_w1 = (const float*)d_in[7];
    const float* msg_b1 = (const float*)d_in[8];
    const float* msg_w2 = (const float*)d_in[9];
    const float* msg_b2 = (const float*)d_in[10];
    const float* rel_w0 = (const float*)d_in[11];
    const float* rel_w1 = (const float*)d_in[12];
    const float* node_w1= (const float*)d_in[13];
    const float* node_b1= (const float*)d_in[14];
    const float* node_w2= (const float*)d_in[15];
    const float* node_b2= (const float*)d_in[16];
    const float* edge_w1= (const float*)d_in[17];
    const float* edge_b1= (const float*)d_in[18];
    const float* edge_w2= (const float*)d_in[19];
    const float* edge_b2= (const float*)d_in[20];
    const float* c0w1   = (const float*)d_in[21];
    const float* c0w2   = (const float*)d_in[23];
    const float* c1w1   = (const float*)d_in[24];
    const float* c1w2   = (const float*)d_in[26];
    const float* lnw    = (const float*)d_in[27];
    const float* lnb    = (const float*)d_in[28];

    float* out       = (float*)d_out;
    float* coord_out = out;                       // [N,L,C,3]   12288
    float* h_out     = out + 12288;               // [N,L,D]     131072
    float* z_out     = out + 12288 + 131072;      // [N,L,L,P]   16777216

    float* ws      = (float*)d_ws;
    float* partial = ws;                          // 16384
    float* rnorm   = ws + 16384;
    float* hA      = ws + 16448;                  // 131072
    float* hB      = hA + 131072;                 // (layout kept)
    float* aggI    = hB + 131072;
    float* aggE    = aggI + 131072;
    float* eA      = aggE + 131072;
    float* eB      = eA + 131072;
    unsigned short* wsA    = (unsigned short*)(eB + 131072);  // 32768 us
    unsigned short* wsMsgA = wsA + 32768;                     // 28672 us
    unsigned short* wsW2A  = wsMsgA + 28672;                  // 16384 us
    unsigned short* wsE1A  = wsW2A + 16384;                   //  8192 us
    unsigned short* wsEW2A = wsE1A + 8192;                    //  8192 us
    unsigned short* h_bf   = wsEW2A + 8192;                   // 131072 us
    unsigned short* z_bf   = h_bf + 131072;                   // 16777216 us (33.5 MB)
    // total ws need with bf16 staging:
    const size_t ws_need = (size_t)((char*)(z_bf + 16777216) - (char*)d_ws);
    const int use_bf = (ws_size >= ws_need) ? 1 : 0;
    // m (bf16) lives in the z_new output region (67 MB exact fit, consumed before k_edge).
    unsigned short* m_bf = (unsigned short*)z_out;

    const int prep_grid = use_bf ? 10160 : 1904;
    k_prep<<<prep_grid, 256, 0, stream>>>(coord, h, z, msg_w1, msg_b1, msg_w2,
                                          edge_w1, edge_w2, c0w1, c1w1,
                                          partial, hA, wsA, wsMsgA, wsW2A,
                                          wsE1A, wsEW2A, h_bf, z_bf);
    k_norm_finish<<<1, 256, 0, stream>>>(partial, rnorm);
    if (use_bf) {
        k_msg_mfma<1><<<1024, 512, 0, stream>>>(coord, h, z, h_bf, z_bf, hA,
                                                wsMsgA, wsW2A, msg_b2, rnorm, m_bf);
    } else {
        k_msg_mfma<0><<<1024, 512, 0, stream>>>(coord, h, z, h_bf, z_bf, hA,
                                                wsMsgA, wsW2A, msg_b2, rnorm, m_bf);
    }
    k_agg<<<1024, 256, 0, stream>>>(m_bf, intra, inter, aggI, aggE);
    k_coord_mfma<<<1024, 512, 0, stream>>>(coord, m_bf, intra, inter, wsA,
                                           c0w2, c1w2, coord_out);
    k_node<<<1024, 128, 0, stream>>>(h, aggI, aggE, rel_w0, rel_w1,
                                     node_w1, node_b1, node_w2, node_b2, lnw, lnb, h_out);
    k_pre_msg<<<1024, 256, 0, stream>>>(h_out, edge_w1, edge_b1, eA, eB);
    if (use_bf) {
        k_edge_mfma<1><<<1024, 512, 0, stream>>>(z, z_bf, eA, eB, wsE1A, wsEW2A, edge_b2, z_out);
    } else {
        k_edge_mfma<0><<<1024, 512, 0, stream>>>(z, z_bf, eA, eB, wsE1A, wsEW2A, edge_b2, z_out);
    }
}

// Round 10
// 252.346 us; speedup vs baseline: 2.2634x; 1.0772x over previous
//
#include <hip/hip_runtime.h>

// SABlock: EGNN-style block. N=4, L=256, D=128, P=64, C=4.
//   k_prep      : fat kernel — norm_partial | pack coord/msg/edge frags | pre_hA | h,z->bf16
//   k_norm_finish : rnorm[16]
//   k_msg_mfma  : v6 — 2048 blocks (128 rows each, no cf loop), GEMM1 split into
//                 rf-halves (a1[4]) to cut peak VGPR below the 128 cap (R9: 33MB spill)
//   k_agg       : aggI/aggE from m_bf (memory-bound)
//   k_coord_mfma: coord MLPs on MFMA + coord update epilogue
//   k_node      : node MLP + LayerNorm
//   k_pre_msg   : eA/eB for edge path (uses h_new)
//   k_edge_mfma : GEMM1 (K=64, z) -> silu(+eA+eB) -> GEMM2 (K=128) -> z_new fp32

#define DEV static __device__ __forceinline__

DEV float silu(float x) { return x / (1.0f + __expf(-x)); }

DEV float bf2f(unsigned short u) {
    unsigned int v = ((unsigned int)u) << 16;
    float f;
    __builtin_memcpy(&f, &v, 4);
    return f;
}
DEV unsigned short f2bf(float f) {
    unsigned int x;
    __builtin_memcpy(&x, &f, 4);
    x += 0x7fffu + ((x >> 16) & 1u);
    return (unsigned short)(x >> 16);
}

struct __align__(8) US4 { unsigned short x, y, z, w; };

typedef __bf16 bf16x8 __attribute__((ext_vector_type(8)));
typedef float  f32x4  __attribute__((ext_vector_type(4)));

DEV bf16x8 cvt8(const float* p) {
    const float4 a = *reinterpret_cast<const float4*>(p);
    const float4 c = *reinterpret_cast<const float4*>(p + 4);
    bf16x8 r;
    r[0] = (__bf16)a.x; r[1] = (__bf16)a.y; r[2] = (__bf16)a.z; r[3] = (__bf16)a.w;
    r[4] = (__bf16)c.x; r[5] = (__bf16)c.y; r[6] = (__bf16)c.z; r[7] = (__bf16)c.w;
    return r;
}

// ---------------- fat prep kernel ----------------
// blk ranges: [0,1024) norm_partial | [1024,1152) pack coord | [1152,1328) pack msg
//             [1328,1392) pack edge | [1392,1904) pre_hA     | [1904,1968) h->bf16
//             [1968,10160) z->bf16 (only when use_bf)
__global__ __launch_bounds__(256) void k_prep(
    const float* __restrict__ coord, const float* __restrict__ h,
    const float* __restrict__ z,
    const float* __restrict__ msg_w1, const float* __restrict__ msg_b1,
    const float* __restrict__ msg_w2,
    const float* __restrict__ edge_w1, const float* __restrict__ edge_w2,
    const float* __restrict__ c0w1, const float* __restrict__ c1w1,
    float* __restrict__ partial, float* __restrict__ hA,
    unsigned short* __restrict__ wsA, unsigned short* __restrict__ wsMsgA,
    unsigned short* __restrict__ wsW2A,
    unsigned short* __restrict__ wE1A, unsigned short* __restrict__ wEW2A,
    unsigned short* __restrict__ h_bf, unsigned short* __restrict__ z_bf)
{
    const int blk = blockIdx.x;
    const int t = threadIdx.x;
    __shared__ float red[4][16];
    __shared__ float hl2[2][128];

    if (blk < 1024) {
        const int r = blk * 256 + t;
        const int b = r >> 16, rem = r & 0xFFFF, i = rem >> 8, j = rem & 255;
        const float* ci = coord + (b * 256 + i) * 12;
        const float* cj = coord + (b * 256 + j) * 12;
        float cd[4][3];
        #pragma unroll
        for (int c = 0; c < 4; ++c)
            #pragma unroll
            for (int x = 0; x < 3; ++x)
                cd[c][x] = ci[c * 3 + x] - cj[c * 3 + x];
        float sq[16];
        #pragma unroll
        for (int m = 0; m < 4; ++m)
            #pragma unroll
            for (int p = 0; p < 4; ++p) {
                float v = cd[m][0] * cd[p][0] + cd[m][1] * cd[p][1] + cd[m][2] * cd[p][2];
                sq[m * 4 + p] = v * v;
            }
        #pragma unroll
        for (int s = 1; s < 64; s <<= 1)
            #pragma unroll
            for (int qq = 0; qq < 16; ++qq)
                sq[qq] += __shfl_xor(sq[qq], s, 64);
        const int wave = t >> 6, lane = t & 63;
        if (lane == 0)
            #pragma unroll
            for (int qq = 0; qq < 16; ++qq) red[wave][qq] = sq[qq];
        __syncthreads();
        if (t < 16)
            partial[blk * 16 + t] = red[0][t] + red[1][t] + red[2][t] + red[3][t];
    } else if (blk < 1152) {
        const int o = (blk - 1024) * 256 + t;         // < 32768
        const int p  = o >> 14;
        const int r  = o & 16383;
        const int jj = r & 7, l = (r >> 3) & 63, rf = (r >> 9) & 7, kk = r >> 12;
        const int k = kk * 32 + ((l >> 4) << 3) + jj;
        const int c = (rf << 4) + (l & 15);
        const float* W = p ? c1w1 : c0w1;
        wsA[o] = f2bf(W[k * 128 + c]);
    } else if (blk < 1328) {
        const int o = (blk - 1152) * 256 + t;         // < 45056
        if (o < 16384) {
            const int jj = o & 7, l = (o >> 3) & 63, rf = (o >> 9) & 7, kk = o >> 12;
            const int k = kk * 32 + ((l >> 4) << 3) + jj;
            const int c = (rf << 4) + (l & 15);
            wsMsgA[o] = f2bf(msg_w1[(128 + k) * 128 + c]);
        } else if (o < 20480) {
            const int o2 = o - 16384;
            const int jj = o2 & 7, l = (o2 >> 3) & 63, rf = (o2 >> 9) & 7;
            const int k = ((l >> 4) << 3) + jj;
            const int c = (rf << 4) + (l & 15);
            wsMsgA[o] = (k < 16) ? f2bf(msg_w1[(256 + k) * 128 + c]) : (unsigned short)0;
        } else if (o < 28672) {
            const int o3 = o - 20480;
            const int jj = o3 & 7, l = (o3 >> 3) & 63, rf = (o3 >> 9) & 7, kk = o3 >> 12;
            const int k = kk * 32 + ((l >> 4) << 3) + jj;
            const int c = (rf << 4) + (l & 15);
            wsMsgA[o] = f2bf(msg_w1[(272 + k) * 128 + c]);
        } else {
            const int o2 = o - 28672;                 // < 16384
            const int jj = o2 & 7, l = (o2 >> 3) & 63, rf = (o2 >> 9) & 7, kk2 = o2 >> 12;
            const int c  = kk2 * 32 + ((l >> 4) << 3) + jj;
            const int c2 = (rf << 4) + (l & 15);
            wsW2A[o2] = f2bf(msg_w2[c * 128 + c2]);
        }
    } else if (blk < 1392) {
        const int o = (blk - 1328) * 256 + t;         // < 16384
        if (o < 8192) {
            const int jj = o & 7, l = (o >> 3) & 63, rf = (o >> 9) & 7, kk = o >> 12;
            const int k = kk * 32 + ((l >> 4) << 3) + jj;
            const int c = (rf << 4) + (l & 15);
            wE1A[o] = f2bf(edge_w1[(256 + k) * 128 + c]);
        } else {
            const int o2 = o - 8192;
            const int jj = o2 & 7, l = (o2 >> 3) & 63, rf = (o2 >> 9) & 3, kk2 = o2 >> 11;
            const int k = kk2 * 32 + ((l >> 4) << 3) + jj;
            const int p = (rf << 4) + (l & 15);
            wEW2A[o2] = f2bf(edge_w2[k * 64 + p]);
        }
    } else if (blk < 1904) {
        const int rr = (blk - 1392) * 2 + (t >> 7);
        const int c = t & 127;
        hl2[t >> 7][c] = h[rr * 128 + c];
        __syncthreads();
        float acc = msg_b1[c];
        #pragma unroll 8
        for (int k = 0; k < 128; ++k) acc += hl2[t >> 7][k] * msg_w1[k * 128 + c];
        hA[rr * 128 + c] = acc;
    } else if (blk < 1968) {
        const int i0 = (blk - 1904) * 2048 + t * 8;   // < 131072
        const bf16x8 v = cvt8(h + i0);
        *reinterpret_cast<bf16x8*>(h_bf + i0) = v;
    } else {
        const size_t i0 = (size_t)(blk - 1968) * 2048 + t * 8;  // < 16777216
        const bf16x8 v = cvt8(z + i0);
        *reinterpret_cast<bf16x8*>(z_bf + i0) = v;
    }
}

__global__ __launch_bounds__(256) void k_norm_finish(const float* __restrict__ partial,
                                                     float* __restrict__ rnorm)
{
    const int t = threadIdx.x;
    const int cc = t & 15, g = t >> 4;
    float s = 0.f;
    for (int k = 0; k < 64; ++k) s += partial[(g * 64 + k) * 16 + cc];
    __shared__ float red[16][17];
    red[g][cc] = s;
    __syncthreads();
    if (t < 16) {
        float tot = 0.f;
        #pragma unroll
        for (int gg = 0; gg < 16; ++gg) tot += red[gg][t];
        rnorm[t] = 1.0f / fmaxf(sqrtf(tot), 1e-12f);
    }
}

// ---------------- row-precompute for edge path ----------------
__global__ __launch_bounds__(256) void k_pre_msg(const float* __restrict__ h,
                                                 const float* __restrict__ w1,
                                                 const float* __restrict__ b1,
                                                 float* __restrict__ hA,
                                                 float* __restrict__ hB)
{
    const int r = blockIdx.x;
    const int t = threadIdx.x;
    const int half = t >> 7, c = t & 127;
    __shared__ float hl[128];
    if (t < 128) hl[t] = h[r * 128 + t];
    __syncthreads();
    const float* W = w1 + half * 128 * 128;
    float acc = half ? 0.f : b1[c];
    #pragma unroll 8
    for (int k = 0; k < 128; ++k) acc += hl[k] * W[k * 128 + c];
    (half ? hB : hA)[r * 128 + c] = acc;
}

// ---------------- message MLP via MFMA (v6: 2048 blocks, split-rf GEMM1) ----------------
template<int ZBF>
__global__ __launch_bounds__(512) void k_msg_mfma(
    const float* __restrict__ coord, const float* __restrict__ h,
    const float* __restrict__ z,
    const unsigned short* __restrict__ h_bf, const unsigned short* __restrict__ z_bf,
    const float* __restrict__ hA,
    const unsigned short* __restrict__ wsMsgA,
    const unsigned short* __restrict__ wsW2A,
    const float* __restrict__ msg_b2, const float* __restrict__ rnorm,
    unsigned short* __restrict__ m_out)
{
    const int blk  = blockIdx.x;
    const int bi   = blk >> 1;
    const int jh   = blk & 1;            // which 128-row half of the (b,i) tile
    const int b    = bi >> 8;
    const int t    = threadIdx.x;
    const int w    = t >> 6, l = t & 63, g = l >> 4, l15 = l & 15;

    __shared__ __align__(16) unsigned short A1[20480];        // 40960 B: hj + rad frags
    __shared__ __align__(16) unsigned short hidm[128 * 136];  // 34816 B
    __shared__ float hAl[128], b2l[128];
    __shared__ float cil[12];
    __shared__ float rnl[16];

    {
        const float4* src = reinterpret_cast<const float4*>(wsMsgA);
        float4* dst = reinterpret_cast<float4*>(A1);
        #pragma unroll
        for (int it = 0; it < 5; ++it) dst[it * 512 + t] = src[it * 512 + t];
    }
    if (t < 12) cil[t] = coord[bi * 12 + t];
    if (t < 16) rnl[t] = rnorm[t];
    if (t < 128)      hAl[t] = hA[bi * 128 + t];
    else if (t < 256) b2l[t - 128] = msg_b2[t - 128];
    __syncthreads();

    const int j   = jh * 128 + w * 16 + l15;   // j in [0,256)
    const int row = w * 16 + l15;
    const size_t rb = (size_t)row * 136;

    // rad B-frag inline (K=32 slot: k = g*8+e, real for k<16, zero-padded above)
    bf16x8 radB;
    {
        const float* cj = coord + (size_t)(b * 256 + j) * 12;
        float cd[12];
        #pragma unroll
        for (int x = 0; x < 12; ++x) cd[x] = cil[x] - cj[x];
        #pragma unroll
        for (int e = 0; e < 8; ++e) {
            const int k = g * 8 + e;
            float v = 0.f;
            if (k < 16) {
                const int mm = k >> 2, pp = k & 3;
                v = (cd[mm*3+0]*cd[pp*3+0] + cd[mm*3+1]*cd[pp*3+1] + cd[mm*3+2]*cd[pp*3+2]) * rnl[k];
            }
            radB[e] = (__bf16)v;
        }
    }

    // GEMM1: K=224, split into rf-halves (a1[4]) to keep peak VGPR < 128
    #pragma unroll 1
    for (int rfh = 0; rfh < 2; ++rfh) {
        asm volatile("" ::: "memory");
        f32x4 a1[4];
        #pragma unroll
        for (int rf2 = 0; rf2 < 4; ++rf2) a1[rf2] = (f32x4){0.f, 0.f, 0.f, 0.f};

        #pragma unroll
        for (int kk = 0; kk < 4; ++kk) {
            bf16x8 bf;
            if constexpr (ZBF) bf = *reinterpret_cast<const bf16x8*>(h_bf + (size_t)(b * 256 + j) * 128 + kk * 32 + g * 8);
            else               bf = cvt8(h + (size_t)(b * 256 + j) * 128 + kk * 32 + g * 8);
            #pragma unroll
            for (int rf2 = 0; rf2 < 4; ++rf2)
                a1[rf2] = __builtin_amdgcn_mfma_f32_16x16x32_bf16(
                    *reinterpret_cast<const bf16x8*>(A1 + ((kk * 8 + rfh * 4 + rf2) * 64 + l) * 8), bf, a1[rf2], 0, 0, 0);
        }
        #pragma unroll
        for (int kk = 0; kk < 2; ++kk) {
            bf16x8 bf;
            if constexpr (ZBF) bf = *reinterpret_cast<const bf16x8*>(z_bf + (size_t)(bi * 256 + j) * 64 + kk * 32 + g * 8);
            else               bf = cvt8(z + (size_t)(bi * 256 + j) * 64 + kk * 32 + g * 8);
            #pragma unroll
            for (int rf2 = 0; rf2 < 4; ++rf2)
                a1[rf2] = __builtin_amdgcn_mfma_f32_16x16x32_bf16(
                    *reinterpret_cast<const bf16x8*>(wsMsgA + 20480 + ((kk * 8 + rfh * 4 + rf2) * 64 + l) * 8), bf, a1[rf2], 0, 0, 0);
        }
        #pragma unroll
        for (int rf2 = 0; rf2 < 4; ++rf2)
            a1[rf2] = __builtin_amdgcn_mfma_f32_16x16x32_bf16(
                *reinterpret_cast<const bf16x8*>(A1 + 16384 + ((rfh * 4 + rf2) * 64 + l) * 8), radB, a1[rf2], 0, 0, 0);

        // hidden = silu(acc + hA[c]) -> bf16 into this lane's hidm row (this half's columns)
        #pragma unroll
        for (int rf2 = 0; rf2 < 4; ++rf2) {
            const int cb = (rfh * 4 + rf2) * 16 + g * 4;
            union { __bf16 b4[4]; unsigned long long u; } pk;
            #pragma unroll
            for (int r = 0; r < 4; ++r) pk.b4[r] = (__bf16)silu(a1[rf2][r] + hAl[cb + r]);
            *reinterpret_cast<unsigned long long*>(hidm + rb + cb) = pk.u;
        }
    }
    __builtin_amdgcn_wave_barrier();

    // GEMM2: m^T = W2^T x hidden^T (W2 A-frags from global/L2)
    f32x4 a2[8];
    #pragma unroll
    for (int rf = 0; rf < 8; ++rf) a2[rf] = (f32x4){0.f, 0.f, 0.f, 0.f};
    #pragma unroll
    for (int kk2 = 0; kk2 < 4; ++kk2) {
        const bf16x8 bf2 = *reinterpret_cast<const bf16x8*>(hidm + rb + kk2 * 32 + g * 8);
        #pragma unroll
        for (int rf = 0; rf < 8; ++rf)
            a2[rf] = __builtin_amdgcn_mfma_f32_16x16x32_bf16(
                *reinterpret_cast<const bf16x8*>(wsW2A + ((kk2 * 8 + rf) * 64 + l) * 8), bf2, a2[rf], 0, 0, 0);
    }
    __builtin_amdgcn_wave_barrier();

    // epilogue: +b2, pack m (bf16) over the hidm row
    #pragma unroll
    for (int rf = 0; rf < 8; ++rf) {
        const int cb = rf * 16 + g * 4;
        union { __bf16 b4[4]; unsigned long long u; } pk;
        #pragma unroll
        for (int r = 0; r < 4; ++r) pk.b4[r] = (__bf16)(a2[rf][r] + b2l[cb + r]);
        *reinterpret_cast<unsigned long long*>(hidm + rb + cb) = pk.u;
    }
    __builtin_amdgcn_wave_barrier();

    // flush wave's 16 rows -> m_out (coalesced: 16 lanes x 16B per row)
    #pragma unroll
    for (int it = 0; it < 4; ++it) {
        const int c2 = it * 64 + l;
        const int rl = c2 >> 4, oct = c2 & 15;
        const uint4 v = *reinterpret_cast<const uint4*>(hidm + (size_t)(w * 16 + rl) * 136 + oct * 8);
        *reinterpret_cast<uint4*>(m_out + ((size_t)(bi * 256 + jh * 128 + w * 16 + rl)) * 128 + oct * 8) = v;
    }
}

// ---------------- masked aggregates from m (memory-bound) ----------------
__global__ __launch_bounds__(256) void k_agg(
    const unsigned short* __restrict__ m_in,
    const float* __restrict__ intra, const float* __restrict__ inter,
    float* __restrict__ aggI, float* __restrict__ aggE)
{
    const int bi = blockIdx.x;
    const int t  = threadIdx.x;
    const int oct = t & 15;
    const int jg  = t >> 4;
    __shared__ float iml[256], eml[256];
    __shared__ float red[2][16][128];
    iml[t] = intra[bi * 256 + t];
    eml[t] = inter[bi * 256 + t];
    __syncthreads();
    float accI[8], accE[8];
    #pragma unroll
    for (int e = 0; e < 8; ++e) { accI[e] = 0.f; accE[e] = 0.f; }
    #pragma unroll 4
    for (int jj = 0; jj < 16; ++jj) {
        const int j = jj * 16 + jg;
        union { uint4 u4; unsigned short us[8]; } v;
        v.u4 = *reinterpret_cast<const uint4*>(m_in + ((size_t)(bi * 256 + j)) * 128 + oct * 8);
        const float wI = iml[j], wE = eml[j];
        #pragma unroll
        for (int e = 0; e < 8; ++e) {
            const float mv = bf2f(v.us[e]);
            accI[e] += mv * wI;
            accE[e] += mv * wE;
        }
    }
    #pragma unroll
    for (int e = 0; e < 8; ++e) {
        red[0][jg][oct * 8 + e] = accI[e];
        red[1][jg][oct * 8 + e] = accE[e];
    }
    __syncthreads();
    if (t < 128) {
        float sI = 0.f, sE = 0.f;
        #pragma unroll
        for (int q = 0; q < 16; ++q) { sI += red[0][q][t]; sE += red[1][q][t]; }
        aggI[bi * 128 + t] = sI;
        aggE[bi * 128 + t] = sE;
    }
}

// ---------------- coord update via MFMA ----------------
__global__ __launch_bounds__(512) void k_coord_mfma(
    const float* __restrict__ coord,
    const unsigned short* __restrict__ m_in,
    const float* __restrict__ intra, const float* __restrict__ inter,
    const unsigned short* __restrict__ wsA,
    const float* __restrict__ c0w2, const float* __restrict__ c1w2,
    float* __restrict__ coord_out)
{
    const int bi = blockIdx.x;
    const int b  = bi >> 8;
    const int t  = threadIdx.x;
    const int w  = t >> 6;
    const int l  = t & 63;
    const int g  = l >> 4;
    const int l15 = l & 15;

    __shared__ __align__(16) unsigned short Apk[2 * 16384];
    __shared__ __align__(16) float W2l[2 * 128 * 4];
    __shared__ float iml[256], eml[256];
    __shared__ float cil[12];
    __shared__ float redC[8][12];
    __shared__ float redD[8];

    {
        const float4* srcA = reinterpret_cast<const float4*>(wsA);
        float4* dstA = reinterpret_cast<float4*>(Apk);
        for (int idx = t; idx < 4096; idx += 512) dstA[idx] = srcA[idx];
        if (t < 512) { W2l[t] = c0w2[t]; W2l[512 + t] = c1w2[t]; }
        if (t < 256) { iml[t] = intra[bi * 256 + t]; eml[t] = inter[bi * 256 + t]; }
        if (t < 12)  cil[t] = coord[bi * 12 + t];
    }
    __syncthreads();

    f32x4 acc[2][2][8];
    #pragma unroll
    for (int p = 0; p < 2; ++p)
        #pragma unroll
        for (int cf = 0; cf < 2; ++cf)
            #pragma unroll
            for (int rf = 0; rf < 8; ++rf)
                acc[p][cf][rf] = (f32x4){0.f, 0.f, 0.f, 0.f};

    #pragma unroll
    for (int kk = 0; kk < 4; ++kk) {
        bf16x8 bfr[2];
        #pragma unroll
        for (int cf = 0; cf < 2; ++cf) {
            const size_t mo = ((size_t)(bi * 256 + w * 32 + cf * 16 + l15)) * 128 + kk * 32 + g * 8;
            bfr[cf] = *reinterpret_cast<const bf16x8*>(m_in + mo);
        }
        #pragma unroll
        for (int rf = 0; rf < 8; ++rf) {
            const bf16x8 a0 = *reinterpret_cast<const bf16x8*>(Apk + ((kk * 8 + rf) * 64 + l) * 8);
            const bf16x8 a1 = *reinterpret_cast<const bf16x8*>(Apk + 16384 + ((kk * 8 + rf) * 64 + l) * 8);
            acc[0][0][rf] = __builtin_amdgcn_mfma_f32_16x16x32_bf16(a0, bfr[0], acc[0][0][rf], 0, 0, 0);
            acc[0][1][rf] = __builtin_amdgcn_mfma_f32_16x16x32_bf16(a0, bfr[1], acc[0][1][rf], 0, 0, 0);
            acc[1][0][rf] = __builtin_amdgcn_mfma_f32_16x16x32_bf16(a1, bfr[0], acc[1][0][rf], 0, 0, 0);
            acc[1][1][rf] = __builtin_amdgcn_mfma_f32_16x16x32_bf16(a1, bfr[1], acc[1][1][rf], 0, 0, 0);
        }
    }

    float wf[2][2][4];
    #pragma unroll
    for (int p = 0; p < 2; ++p)
        #pragma unroll
        for (int cf = 0; cf < 2; ++cf)
            #pragma unroll
            for (int pc = 0; pc < 4; ++pc) wf[p][cf][pc] = 0.f;

    #pragma unroll
    for (int p = 0; p < 2; ++p)
        #pragma unroll
        for (int rf = 0; rf < 8; ++rf)
            #pragma unroll
            for (int r = 0; r < 4; ++r) {
                const int c = rf * 16 + g * 4 + r;
                const float4 w2 = *reinterpret_cast<const float4*>(&W2l[(p * 128 + c) * 4]);
                #pragma unroll
                for (int cf = 0; cf < 2; ++cf) {
                    const float hid = silu(acc[p][cf][rf][r]);
                    wf[p][cf][0] += hid * w2.x;
                    wf[p][cf][1] += hid * w2.y;
                    wf[p][cf][2] += hid * w2.z;
                    wf[p][cf][3] += hid * w2.w;
                }
            }

    float accC[12];
    #pragma unroll
    for (int q2 = 0; q2 < 12; ++q2) accC[q2] = 0.f;
    float dacc = 0.f;

    #pragma unroll
    for (int cf = 0; cf < 2; ++cf) {
        float w0c[4], w1c[4];
        #pragma unroll
        for (int pc = 0; pc < 4; ++pc) { w0c[pc] = wf[0][cf][pc]; w1c[pc] = wf[1][cf][pc]; }
        #pragma unroll
        for (int pc = 0; pc < 4; ++pc) {
            w0c[pc] += __shfl_xor(w0c[pc], 16, 64); w0c[pc] += __shfl_xor(w0c[pc], 32, 64);
            w1c[pc] += __shfl_xor(w1c[pc], 16, 64); w1c[pc] += __shfl_xor(w1c[pc], 32, 64);
        }
        const int j = w * 32 + cf * 16 + l15;
        const float im = iml[j], em = eml[j];
        float wt[4];
        #pragma unroll
        for (int pc = 0; pc < 4; ++pc) wt[pc] = w0c[pc] * im + w1c[pc] * em;
        const float* cjp = coord + (size_t)(b * 256 + j) * 12;
        const float4 cj0 = *reinterpret_cast<const float4*>(cjp);
        const float4 cj1 = *reinterpret_cast<const float4*>(cjp + 4);
        const float4 cj2 = *reinterpret_cast<const float4*>(cjp + 8);
        accC[0]  += (cil[0]  - cj0.x) * wt[0];
        accC[1]  += (cil[1]  - cj0.y) * wt[0];
        accC[2]  += (cil[2]  - cj0.z) * wt[0];
        accC[3]  += (cil[3]  - cj0.w) * wt[1];
        accC[4]  += (cil[4]  - cj1.x) * wt[1];
        accC[5]  += (cil[5]  - cj1.y) * wt[1];
        accC[6]  += (cil[6]  - cj1.z) * wt[2];
        accC[7]  += (cil[7]  - cj1.w) * wt[2];
        accC[8]  += (cil[8]  - cj2.x) * wt[2];
        accC[9]  += (cil[9]  - cj2.y) * wt[3];
        accC[10] += (cil[10] - cj2.z) * wt[3];
        accC[11] += (cil[11] - cj2.w) * wt[3];
        dacc += im + em;
    }
    #pragma unroll
    for (int s = 1; s < 16; s <<= 1) {
        #pragma unroll
        for (int q2 = 0; q2 < 12; ++q2) accC[q2] += __shfl_xor(accC[q2], s, 64);
        dacc += __shfl_xor(dacc, s, 64);
    }
    if (l == 0) {
        #pragma unroll
        for (int q2 = 0; q2 < 12; ++q2) redC[w][q2] = accC[q2];
        redD[w] = dacc;
    }
    __syncthreads();
    if (t < 12) {
        float s = 0.f, d = 0.f;
        #pragma unroll
        for (int ww = 0; ww < 8; ++ww) { s += redC[ww][t]; d += redD[ww]; }
        d += 2.56e-4f;   // L * 1e-6
        coord_out[bi * 12 + t] = coord[bi * 12 + t] + s / d;
    }
}

// ---------------- node update + LayerNorm ----------------
__global__ __launch_bounds__(128) void k_node(
    const float* __restrict__ h,
    const float* __restrict__ aggI, const float* __restrict__ aggE,
    const float* __restrict__ rel0, const float* __restrict__ rel1,
    const float* __restrict__ nw1, const float* __restrict__ nb1,
    const float* __restrict__ nw2, const float* __restrict__ nb2,
    const float* __restrict__ lnw, const float* __restrict__ lnb,
    float* __restrict__ h_out)
{
    const int r = blockIdx.x, t = threadIdx.x;
    __shared__ float hl[128], aIl[128], aEl[128], a0l[128], a1l[128], hidl[128];
    hl[t]  = h[r * 128 + t];
    aIl[t] = aggI[r * 128 + t];
    aEl[t] = aggE[r * 128 + t];
    __syncthreads();
    float a0 = 0.f, a1 = 0.f;
    #pragma unroll 8
    for (int k = 0; k < 128; ++k) { a0 += aIl[k] * rel0[k * 128 + t]; a1 += aEl[k] * rel1[k * 128 + t]; }
    a0l[t] = a0; a1l[t] = a1;
    __syncthreads();
    float pre = nb1[t];
    #pragma unroll 8
    for (int k = 0; k < 128; ++k) pre += hl[k]  * nw1[k * 128 + t];
    #pragma unroll 8
    for (int k = 0; k < 128; ++k) pre += a0l[k] * nw1[(128 + k) * 128 + t];
    #pragma unroll 8
    for (int k = 0; k < 128; ++k) pre += a1l[k] * nw1[(256 + k) * 128 + t];
    hidl[t] = silu(pre);
    __syncthreads();
    float upd = nb2[t];
    #pragma unroll 8
    for (int k = 0; k < 128; ++k) upd += hidl[k] * nw2[k * 128 + t];
    const float x = hl[t] + upd;
    float s = x, s2 = x * x;
    #pragma unroll
    for (int d = 1; d < 64; d <<= 1) { s += __shfl_xor(s, d, 64); s2 += __shfl_xor(s2, d, 64); }
    __shared__ float rs[2], rs2[2];
    const int wv = t >> 6;
    if ((t & 63) == 0) { rs[wv] = s; rs2[wv] = s2; }
    __syncthreads();
    const float S = rs[0] + rs[1], S2 = rs2[0] + rs2[1];
    const float mu = S * (1.f / 128.f);
    const float var = S2 * (1.f / 128.f) - mu * mu;
    h_out[r * 128 + t] = (x - mu) * rsqrtf(var + 1e-5f) * lnw[t] + lnb[t];
}

// ---------------- edge update via MFMA ----------------
template<int ZBF>
__global__ __launch_bounds__(512) void k_edge_mfma(
    const float* __restrict__ z, const unsigned short* __restrict__ z_bf,
    const float* __restrict__ eA, const float* __restrict__ eB,
    const unsigned short* __restrict__ wE1A,
    const unsigned short* __restrict__ wEW2A,
    const float* __restrict__ eb2,
    float* __restrict__ z_out)
{
    const int bi = blockIdx.x;
    const int b  = bi >> 8;
    const int t  = threadIdx.x;
    const int w  = t >> 6, l = t & 63, g = l >> 4, l15 = l & 15;

    __shared__ __align__(16) unsigned short hidm[256 * 136];  // rows reused fp32 for z_new
    __shared__ float eAl[128];
    __shared__ float eb2l[64];

    if (t < 128)      eAl[t] = eA[bi * 128 + t];
    else if (t < 192) eb2l[t - 128] = eb2[t - 128];
    __syncthreads();

    #pragma unroll 1
    for (int cf = 0; cf < 2; ++cf) {
        asm volatile("" ::: "memory");
        const int j = w * 32 + cf * 16 + l15;

        f32x4 a1[8];
        #pragma unroll
        for (int rf = 0; rf < 8; ++rf) a1[rf] = (f32x4){0.f, 0.f, 0.f, 0.f};
        #pragma unroll
        for (int kk = 0; kk < 2; ++kk) {
            bf16x8 bf;
            if constexpr (ZBF) bf = *reinterpret_cast<const bf16x8*>(z_bf + (size_t)(bi * 256 + j) * 64 + kk * 32 + g * 8);
            else               bf = cvt8(z + (size_t)(bi * 256 + j) * 64 + kk * 32 + g * 8);
            #pragma unroll
            for (int rf = 0; rf < 8; ++rf)
                a1[rf] = __builtin_amdgcn_mfma_f32_16x16x32_bf16(
                    *reinterpret_cast<const bf16x8*>(wE1A + ((kk * 8 + rf) * 64 + l) * 8), bf, a1[rf], 0, 0, 0);
        }

        const float* eBrow = eB + (size_t)(b * 256 + j) * 128;
        #pragma unroll
        for (int rf = 0; rf < 8; ++rf) {
            const int cb = rf * 16 + g * 4;
            const float4 e4 = *reinterpret_cast<const float4*>(eBrow + cb);
            union { __bf16 b4[4]; unsigned long long u; } pk;
            pk.b4[0] = (__bf16)silu(a1[rf][0] + eAl[cb + 0] + e4.x);
            pk.b4[1] = (__bf16)silu(a1[rf][1] + eAl[cb + 1] + e4.y);
            pk.b4[2] = (__bf16)silu(a1[rf][2] + eAl[cb + 2] + e4.z);
            pk.b4[3] = (__bf16)silu(a1[rf][3] + eAl[cb + 3] + e4.w);
            *reinterpret_cast<unsigned long long*>(hidm + (size_t)j * 136 + cb) = pk.u;
        }
        __builtin_amdgcn_wave_barrier();

        f32x4 a2[4];
        #pragma unroll
        for (int rf = 0; rf < 4; ++rf) a2[rf] = (f32x4){0.f, 0.f, 0.f, 0.f};
        #pragma unroll
        for (int kk2 = 0; kk2 < 4; ++kk2) {
            const bf16x8 bf2 = *reinterpret_cast<const bf16x8*>(hidm + (size_t)j * 136 + kk2 * 32 + g * 8);
            #pragma unroll
            for (int rf = 0; rf < 4; ++rf)
                a2[rf] = __builtin_amdgcn_mfma_f32_16x16x32_bf16(
                    *reinterpret_cast<const bf16x8*>(wEW2A + ((kk2 * 4 + rf) * 64 + l) * 8), bf2, a2[rf], 0, 0, 0);
        }
        __builtin_amdgcn_wave_barrier();

        float* zst = reinterpret_cast<float*>(hidm + (size_t)j * 136);
        #pragma unroll
        for (int rf = 0; rf < 4; ++rf) {
            const int p0 = rf * 16 + g * 4;
            float4 v;
            v.x = a2[rf][0] + eb2l[p0 + 0];
            v.y = a2[rf][1] + eb2l[p0 + 1];
            v.z = a2[rf][2] + eb2l[p0 + 2];
            v.w = a2[rf][3] + eb2l[p0 + 3];
            *reinterpret_cast<float4*>(zst + p0) = v;
        }
        __builtin_amdgcn_wave_barrier();
    }

    #pragma unroll
    for (int it = 0; it < 8; ++it) {
        const int chunk = it * 64 + l;
        const int jl = chunk >> 4, oct = chunk & 15;
        const int jr = w * 32 + jl;
        const float4 v = *reinterpret_cast<const float4*>(
            reinterpret_cast<const float*>(hidm + (size_t)jr * 136) + oct * 4);
        *reinterpret_cast<float4*>(z_out + (size_t)(bi * 256 + jr) * 64 + oct * 4) = v;
    }
}

extern "C" void kernel_launch(void* const* d_in, const int* in_sizes, int n_in,
                              void* d_out, int out_size, void* d_ws, size_t ws_size,
                              hipStream_t stream)
{
    (void)in_sizes; (void)n_in; (void)out_size;
    const float* coord  = (const float*)d_in[2];
    const float* h      = (const float*)d_in[3];
    const float* z      = (const float*)d_in[4];
    const float* intra  = (const float*)d_in[5];
    const float* inter  = (const float*)d_in[6];
    const float* msg_w1 = (const float*)d_in[7];
    const float* msg_b1 = (const float*)d_in[8];
    const float* msg_w2 = (const float*)d_in[9];
    const float* msg_b2 = (const float*)d_in[10];
    const float* rel_w0 = (const float*)d_in[11];
    const float* rel_w1 = (const float*)d_in[12];
    const float* node_w1= (const float*)d_in[13];
    const float* node_b1= (const float*)d_in[14];
    const float* node_w2= (const float*)d_in[15];
    const float* node_b2= (const float*)d_in[16];
    const float* edge_w1= (const float*)d_in[17];
    const float* edge_b1= (const float*)d_in[18];
    const float* edge_w2= (const float*)d_in[19];
    const float* edge_b2= (const float*)d_in[20];
    const float* c0w1   = (const float*)d_in[21];
    const float* c0w2   = (const float*)d_in[23];
    const float* c1w1   = (const float*)d_in[24];
    const float* c1w2   = (const float*)d_in[26];
    const float* lnw    = (const float*)d_in[27];
    const float* lnb    = (const float*)d_in[28];

    float* out       = (float*)d_out;
    float* coord_out = out;                       // [N,L,C,3]   12288
    float* h_out     = out + 12288;               // [N,L,D]     131072
    float* z_out     = out + 12288 + 131072;      // [N,L,L,P]   16777216

    float* ws      = (float*)d_ws;
    float* partial = ws;                          // 16384
    float* rnorm   = ws + 16384;
    float* hA      = ws + 16448;                  // 131072
    float* hB      = hA + 131072;                 // (layout kept)
    float* aggI    = hB + 131072;
    float* aggE    = aggI + 131072;
    float* eA      = aggE + 131072;
    float* eB      = eA + 131072;
    unsigned short* wsA    = (unsigned short*)(eB + 131072);  // 32768 us
    unsigned short* wsMsgA = wsA + 32768;                     // 28672 us
    unsigned short* wsW2A  = wsMsgA + 28672;                  // 16384 us
    unsigned short* wsE1A  = wsW2A + 16384;                   //  8192 us
    unsigned short* wsEW2A = wsE1A + 8192;                    //  8192 us
    unsigned short* h_bf   = wsEW2A + 8192;                   // 131072 us
    unsigned short* z_bf   = h_bf + 131072;                   // 16777216 us (33.5 MB)
    const size_t ws_need = (size_t)((char*)(z_bf + 16777216) - (char*)d_ws);
    const int use_bf = (ws_size >= ws_need) ? 1 : 0;
    // m (bf16) lives in the z_new output region (67 MB exact fit, consumed before k_edge).
    unsigned short* m_bf = (unsigned short*)z_out;

    const int prep_grid = use_bf ? 10160 : 1904;
    k_prep<<<prep_grid, 256, 0, stream>>>(coord, h, z, msg_w1, msg_b1, msg_w2,
                                          edge_w1, edge_w2, c0w1, c1w1,
                                          partial, hA, wsA, wsMsgA, wsW2A,
                                          wsE1A, wsEW2A, h_bf, z_bf);
    k_norm_finish<<<1, 256, 0, stream>>>(partial, rnorm);
    if (use_bf) {
        k_msg_mfma<1><<<2048, 512, 0, stream>>>(coord, h, z, h_bf, z_bf, hA,
                                                wsMsgA, wsW2A, msg_b2, rnorm, m_bf);
    } else {
        k_msg_mfma<0><<<2048, 512, 0, stream>>>(coord, h, z, h_bf, z_bf, hA,
                                                wsMsgA, wsW2A, msg_b2, rnorm, m_bf);
    }
    k_agg<<<1024, 256, 0, stream>>>(m_bf, intra, inter, aggI, aggE);
    k_coord_mfma<<<1024, 512, 0, stream>>>(coord, m_bf, intra, inter, wsA,
                                           c0w2, c1w2, coord_out);
    k_node<<<1024, 128, 0, stream>>>(h, aggI, aggE, rel_w0, rel_w1,
                                     node_w1, node_b1, node_w2, node_b2, lnw, lnb, h_out);
    k_pre_msg<<<1024, 256, 0, stream>>>(h_out, edge_w1, edge_b1, eA, eB);
    if (use_bf) {
        k_edge_mfma<1><<<1024, 512, 0, stream>>>(z, z_bf, eA, eB, wsE1A, wsEW2A, edge_b2, z_out);
    } else {
        k_edge_mfma<0><<<1024, 512, 0, stream>>>(z, z_bf, eA, eB, wsE1A, wsEW2A, edge_b2, z_out);
    }
}